// Round 1
// 3138.068 us; speedup vs baseline: 1.7092x; 1.7092x over previous
//
#include <hip/hip_runtime.h>
#include <hip/hip_bf16.h>
#include <math.h>

#define B_ 8
#define C_ 192
#define H_ 192
#define W_ 192
#define NWH 24   // windows per spatial dim

typedef __hip_bfloat16 bf16;
typedef short bf16x8 __attribute__((ext_vector_type(8)));
typedef short bf16x4 __attribute__((ext_vector_type(4)));
typedef float f32x4 __attribute__((ext_vector_type(4)));

__device__ __forceinline__ float bf2f(bf16 v) { return __bfloat162float(v); }
__device__ __forceinline__ bf16 f2bf(float v) { return __float2bfloat16(v); }

union bu { bf16 b; ushort u; };

// ---------------------------------------------------------------------------
// K0: bias MLP + gather (block 0) and cw2 repack to bf16 [tap][co][ci]
// ---------------------------------------------------------------------------
__global__ __launch_bounds__(256) void k_prep(
    const float* __restrict__ b1_w, const float* __restrict__ b1_b,
    const float* __restrict__ b2_w, const float* __restrict__ b2_b,
    const int* __restrict__ bias_index, const float* __restrict__ bias_delta,
    const float* __restrict__ cw2,
    float* __restrict__ bias_out, bf16* __restrict__ wpk) {
  int t = threadIdx.x;
  if (blockIdx.x == 0) {
    __shared__ float val[256];
    if (t < 225) {
      float dy = bias_delta[2 * t], dx = bias_delta[2 * t + 1];
      float acc = b2_b[0];
      for (int j = 0; j < 16; ++j) {
        float hj = b1_w[2 * j] * dy + b1_w[2 * j + 1] * dx + b1_b[j];
        float g = 0.5f * hj * (1.0f + erff(hj * 0.7071067811865475f));  // exact GELU
        acc += g * b2_w[j];
      }
      val[t] = acc;
    }
    __syncthreads();
    for (int i = t; i < 4096; i += 256) {
      int idx = bias_index[i];
      idx = min(max(idx, 0), 224);
      bias_out[i] = val[idx];
    }
  }
  // repack cw2 [co][ci][9] -> bf16 wpk[tap][co][ci]
  int idx = blockIdx.x * 256 + t;
  if (idx < 9 * 192 * 192) {
    int tp = idx / 36864;
    int r = idx % 36864;
    int co = r / 192, ci = r % 192;
    wpk[idx] = f2bf(cw2[(co * 192 + ci) * 9 + tp]);
  }
}

// ---------------------------------------------------------------------------
// K1: per-pixel LayerNorm over C + QKV GEMM.  Block = (b, h, 64-wide w tile).
// ---------------------------------------------------------------------------
__global__ __launch_bounds__(256) void k_ln_qkv(
    const float* __restrict__ x, const float* __restrict__ ln_w,
    const float* __restrict__ qkv_w, const float* __restrict__ qkv_b,
    bf16* __restrict__ qkv) {
  __shared__ float xs[64 * 193];   // [pixel][c], stride 193 (odd -> conflict-free)
  __shared__ float red[2 * 256];
  int t = threadIdx.x;
  int blk = blockIdx.x;
  int b = blk / (H_ * 3);
  int rem = blk % (H_ * 3);
  int h = rem / 3;
  int w0 = (rem % 3) * 64;
  int p = t & 63, q = t >> 6;
  const float* xb = x + ((size_t)b * C_ * H_ + h) * W_ + w0;
  for (int c = q; c < C_; c += 4)
    xs[p * 193 + c] = xb[(size_t)c * H_ * W_ + p];
  __syncthreads();
  float s = 0.f, s2 = 0.f;
  for (int c = q * 48; c < q * 48 + 48; ++c) {
    float v = xs[p * 193 + c];
    s += v; s2 += v * v;
  }
  red[q * 64 + p] = s;
  red[256 + q * 64 + p] = s2;
  __syncthreads();
  float mu = (red[p] + red[64 + p] + red[128 + p] + red[192 + p]) * (1.f / 192.f);
  float m2 = (red[256 + p] + red[320 + p] + red[384 + p] + red[448 + p]) * (1.f / 192.f);
  float rsig = rsqrtf(m2 - mu * mu + 1e-5f);
  for (int c = q * 48; c < q * 48 + 48; ++c)
    xs[p * 193 + c] = (xs[p * 193 + c] - mu) * rsig * ln_w[c];
  __syncthreads();
  float acc[48];
#pragma unroll
  for (int j = 0; j < 48; ++j) acc[j] = qkv_b[q * 48 + j];
  for (int c = 0; c < C_; c += 4) {
    float xv0 = xs[p * 193 + c], xv1 = xs[p * 193 + c + 1];
    float xv2 = xs[p * 193 + c + 2], xv3 = xs[p * 193 + c + 3];
    const float* wb = qkv_w + (q * 48) * C_ + c;
#pragma unroll
    for (int j = 0; j < 48; ++j) {
      float4 w4 = *(const float4*)(wb + j * C_);
      acc[j] = fmaf(xv0, w4.x, fmaf(xv1, w4.y, fmaf(xv2, w4.z, fmaf(xv3, w4.w, acc[j]))));
    }
  }
  bf16* ob = qkv + ((size_t)b * C_ * H_ + h) * W_ + w0;
#pragma unroll
  for (int j = 0; j < 48; ++j)
    ob[(size_t)(q * 48 + j) * H_ * W_ + p] = f2bf(acc[j]);
}

// ---------------------------------------------------------------------------
// K2: windowed attention + proj + residual.  Block = one 8x8 window.
// ---------------------------------------------------------------------------
__global__ __launch_bounds__(256) void k_attn(
    const bf16* __restrict__ qkv, const float* __restrict__ bias,
    const float* __restrict__ proj_w, const float* __restrict__ proj_b,
    const float* __restrict__ x, float* __restrict__ out) {
  __shared__ float qs[64 * 17], ks[64 * 17], vs[64 * 17];
  __shared__ float ss[64 * 67];
  __shared__ float os[64 * 65];
  int t = threadIdx.x;
  int blk = blockIdx.x;
  int b = blk / (NWH * NWH);
  int rem = blk % (NWH * NWH);
  int wh = rem / NWH, ww = rem % NWH;
  int h0 = wh * 8, w0 = ww * 8;
  size_t base = ((size_t)b * C_ * H_ + h0) * W_ + w0;
  int p = t & 63, g = t >> 6;

  for (int hd = 0; hd < 4; ++hd) {
    for (int k = 0; k < 4; ++k) {
      int e = k * 256 + t;
      int pp = e & 63, j = e >> 6;
      int i = pp >> 3, jj = pp & 7;
      size_t off = base + (size_t)i * W_ + jj;
      qs[pp * 17 + j] = bf2f(qkv[off + (size_t)(hd * 16 + j) * H_ * W_]);
      ks[pp * 17 + j] = bf2f(qkv[off + (size_t)(64 + hd * 16 + j) * H_ * W_]);
      vs[pp * 17 + j] = bf2f(qkv[off + (size_t)(128 + hd * 16 + j) * H_ * W_]);
    }
    __syncthreads();
    float qv[16];
#pragma unroll
    for (int j = 0; j < 16; ++j) qv[j] = qs[p * 17 + j];
    for (int mm = 0; mm < 16; ++mm) {
      int m = g * 16 + mm;
      float sc = 0.f;
#pragma unroll
      for (int j = 0; j < 16; ++j) sc += qv[j] * ks[m * 17 + j];
      ss[p * 67 + m] = sc * 0.25f + bias[p * 64 + m];
    }
    __syncthreads();
    if (t < 64) {
      float mx = -1e30f;
      for (int m = 0; m < 64; ++m) mx = fmaxf(mx, ss[t * 67 + m]);
      float sum = 0.f;
      for (int m = 0; m < 64; ++m) {
        float e_ = __expf(ss[t * 67 + m] - mx);
        ss[t * 67 + m] = e_; sum += e_;
      }
      float inv = 1.f / sum;
      for (int m = 0; m < 64; ++m) ss[t * 67 + m] *= inv;
    }
    __syncthreads();
    float oa[4] = {0.f, 0.f, 0.f, 0.f};
    for (int m = 0; m < 64; ++m) {
      float sv = ss[p * 67 + m];
#pragma unroll
      for (int jj = 0; jj < 4; ++jj) oa[jj] += sv * vs[m * 17 + g * 4 + jj];
    }
#pragma unroll
    for (int jj = 0; jj < 4; ++jj) os[p * 65 + hd * 16 + g * 4 + jj] = oa[jj];
    __syncthreads();
  }
  float acc[48];
#pragma unroll
  for (int j = 0; j < 48; ++j) acc[j] = proj_b[g * 48 + j];
  for (int m = 0; m < 64; m += 4) {
    float o0 = os[p * 65 + m], o1 = os[p * 65 + m + 1];
    float o2 = os[p * 65 + m + 2], o3 = os[p * 65 + m + 3];
    const float* wb = proj_w + (g * 48) * 64 + m;
#pragma unroll
    for (int j = 0; j < 48; ++j) {
      float4 w4 = *(const float4*)(wb + j * 64);
      acc[j] = fmaf(o0, w4.x, fmaf(o1, w4.y, fmaf(o2, w4.z, fmaf(o3, w4.w, acc[j]))));
    }
  }
  int i = p >> 3, jj = p & 7;
  size_t pb = base + (size_t)i * W_ + jj;
#pragma unroll
  for (int j = 0; j < 48; ++j) {
    size_t off = pb + (size_t)(g * 48 + j) * H_ * W_;
    out[off] = acc[j] + x[off];
  }
}

// ---------------------------------------------------------------------------
// K3: 1x1 conv (C->2C) + GLU as implicit GEMM on MFMA.
// M=384 out-ch, N=64 pixels (one h row, 64-wide w tile), K=192.
// Block = 256 thr (4 waves).  Wave w owns a-channels [w*48,w*48+48) (3 m-tiles)
// and the matching g-channels +192 (3 m-tiles) so GLU pairing is wave-local.
// Weights converted fp32->bf16 in-register (broadcast loads, L2-resident).
// Output y is CHANNELS-LAST bf16: y[((b*H+h)*W+w)*192 + c]  (for conv2 MFMA)
// ---------------------------------------------------------------------------
__global__ __launch_bounds__(256) void k_conv1_glu(
    const float* __restrict__ xa, const float* __restrict__ cw1,
    const float* __restrict__ cb1, bf16* __restrict__ y) {
  __shared__ ushort xs[64 * 204];   // bf16 [pixel][ci], stride 204 (2-way alias max)
  int t = threadIdx.x;
  int blk = blockIdx.x;
  int b = blk / (H_ * 3);
  int rem = blk % (H_ * 3);
  int h = rem / 3;
  int w0 = (rem % 3) * 64;
  int p = t & 63, q = t >> 6;
  const float* xb = xa + ((size_t)b * C_ * H_ + h) * W_ + w0;
  for (int c = q; c < C_; c += 4) {
    bu cv; cv.b = f2bf(xb[(size_t)c * H_ * W_ + p]);
    xs[p * 204 + c] = cv.u;
  }
  __syncthreads();

  int wave = t >> 6, lane = t & 63;
  int col16 = lane & 15, quad = lane >> 4;
  // acc[mi]: mi 0..2 -> a channels (co = wave*48 + mi*16), mi 3..5 -> g (+192)
  f32x4 acc[6][4];
#pragma unroll
  for (int mi = 0; mi < 6; ++mi) {
    int cob = (mi < 3) ? wave * 48 + mi * 16 : 192 + wave * 48 + (mi - 3) * 16;
#pragma unroll
    for (int r = 0; r < 4; ++r) {
      float bv = cb1[cob + quad * 4 + r];
#pragma unroll
      for (int ni = 0; ni < 4; ++ni) acc[mi][ni][r] = bv;
    }
  }

  for (int ksi = 0; ksi < 6; ++ksi) {
    // B fragments: 4 n-tiles of 16 pixels, k = ksi*32 + quad*8 .. +8
    bf16x8 bfr[4];
#pragma unroll
    for (int ni = 0; ni < 4; ++ni) {
      const bf16x4* src =
          (const bf16x4*)(&xs[(ni * 16 + col16) * 204 + ksi * 32 + quad * 8]);
      union { bf16x8 v; bf16x4 h[2]; } u;
      u.h[0] = src[0];
      u.h[1] = src[1];
      bfr[ni] = u.v;
    }
#pragma unroll
    for (int mi = 0; mi < 6; ++mi) {
      int cob = (mi < 3) ? wave * 48 + mi * 16 : 192 + wave * 48 + (mi - 3) * 16;
      const float* wsrc = cw1 + (size_t)(cob + col16) * 192 + ksi * 32 + quad * 8;
      float4 wa = *(const float4*)(wsrc);
      float4 wb = *(const float4*)(wsrc + 4);
      bf16x8 a;
      {
        bu cv;
        cv.b = f2bf(wa.x); a[0] = (short)cv.u;
        cv.b = f2bf(wa.y); a[1] = (short)cv.u;
        cv.b = f2bf(wa.z); a[2] = (short)cv.u;
        cv.b = f2bf(wa.w); a[3] = (short)cv.u;
        cv.b = f2bf(wb.x); a[4] = (short)cv.u;
        cv.b = f2bf(wb.y); a[5] = (short)cv.u;
        cv.b = f2bf(wb.z); a[6] = (short)cv.u;
        cv.b = f2bf(wb.w); a[7] = (short)cv.u;
      }
#pragma unroll
      for (int ni = 0; ni < 4; ++ni)
        acc[mi][ni] =
            __builtin_amdgcn_mfma_f32_16x16x32_bf16(a, bfr[ni], acc[mi][ni], 0, 0, 0);
    }
  }
  __syncthreads();   // all xs reads done; reuse xs for output staging

  // GLU epilogue: res = a * sigmoid(g).  D layout: row(co)=quad*4+r, col(px)=col16
#pragma unroll
  for (int mi = 0; mi < 3; ++mi) {
#pragma unroll
    for (int ni = 0; ni < 4; ++ni) {
      int px = ni * 16 + col16;
      int co = wave * 48 + mi * 16 + quad * 4;
#pragma unroll
      for (int rr = 0; rr < 2; ++rr) {
        float a0 = acc[mi][ni][rr * 2], a1 = acc[mi][ni][rr * 2 + 1];
        float g0 = acc[mi + 3][ni][rr * 2], g1 = acc[mi + 3][ni][rr * 2 + 1];
        float r0 = a0 / (1.f + __expf(-g0));
        float r1 = a1 / (1.f + __expf(-g1));
        bu c0, c1;
        c0.b = f2bf(r0); c1.b = f2bf(r1);
        *(uint*)(&xs[px * 204 + co + rr * 2]) = (uint)c0.u | ((uint)c1.u << 16);
      }
    }
  }
  __syncthreads();
  // coalesced channels-last store: 64 px x 24 chunks of 8 bf16
  ushort* yb = (ushort*)y + (((size_t)b * H_ + h) * W_ + w0) * 192;
#pragma unroll
  for (int i = 0; i < 6; ++i) {
    int e = i * 256 + t;
    int px = e / 24, ch = e % 24;
    uint u0 = *(const uint*)(&xs[px * 204 + ch * 8]);
    uint u1 = *(const uint*)(&xs[px * 204 + ch * 8 + 2]);
    uint u2 = *(const uint*)(&xs[px * 204 + ch * 8 + 4]);
    uint u3 = *(const uint*)(&xs[px * 204 + ch * 8 + 6]);
    uint4 pk; pk.x = u0; pk.y = u1; pk.z = u2; pk.w = u3;
    *(uint4*)(yb + (size_t)px * 192 + ch * 8) = pk;
  }
}

// ---------------------------------------------------------------------------
// K4: 3x3 conv as implicit GEMM on MFMA.  M=192 out-ch, N=64 pixels (4 rows x
// 16 cols), K=9*192.  Block = 256 thr (4 waves); wave w: m-tiles {3w..3w+2},
// all 4 n-tiles.  LDS: halo tile channels-last, pad 204 (<=2-way bank alias).
// ---------------------------------------------------------------------------
__global__ __launch_bounds__(256) void k_conv2(
    const bf16* __restrict__ y, const bf16* __restrict__ wpk,
    const float* __restrict__ cb2, float* __restrict__ out) {
  __shared__ ushort yl[6 * 18 * 204];  // [halo pixel][ci], 44064 B
  int t = threadIdx.x;
  int blk = blockIdx.x;
  int b = blk / (48 * 12);
  int rem = blk % (48 * 12);
  int h0 = (rem / 12) * 4;
  int w0 = (rem % 12) * 16;
  // stage 108 halo pixels x 192 ci (8B chunks, replicate-clamped)
  const ushort* yg = (const ushort*)y;
  for (int e = t; e < 108 * 48; e += 256) {
    int p = e / 48, c8 = e % 48;
    int prow = p / 18, pcol = p % 18;
    int gr = min(max(h0 - 1 + prow, 0), H_ - 1);
    int gc = min(max(w0 - 1 + pcol, 0), W_ - 1);
    *(float2*)(&yl[p * 204 + c8 * 4]) =
        *(const float2*)(yg + (((size_t)b * H_ + gr) * W_ + gc) * 192 + c8 * 4);
  }
  __syncthreads();
  int wave = t >> 6, lane = t & 63;
  int col16 = lane & 15, quad = lane >> 4;
  f32x4 acc[3][4];
#pragma unroll
  for (int mi = 0; mi < 3; ++mi) {
#pragma unroll
    for (int r = 0; r < 4; ++r) {
      float bv = cb2[(wave * 3 + mi) * 16 + quad * 4 + r];
#pragma unroll
      for (int ni = 0; ni < 4; ++ni) acc[mi][ni][r] = bv;
    }
  }
  const ushort* wq = (const ushort*)wpk;
  for (int tap = 0; tap < 9; ++tap) {
    int dy = tap / 3, dx = tap % 3;
#pragma unroll
    for (int ks = 0; ks < 6; ++ks) {
      bf16x8 a[3];
#pragma unroll
      for (int mi = 0; mi < 3; ++mi) {
        int co = (wave * 3 + mi) * 16 + col16;
        a[mi] = *(const bf16x8*)(wq + ((size_t)tap * 192 + co) * 192 + ks * 32 + quad * 8);
      }
      bf16x8 bfr[4];
#pragma unroll
      for (int ni = 0; ni < 4; ++ni) {
        int p = (ni + dy) * 18 + col16 + dx;
        const bf16x4* src = (const bf16x4*)(&yl[p * 204 + ks * 32 + quad * 8]);
        union { bf16x8 v; bf16x4 h[2]; } u;
        u.h[0] = src[0];
        u.h[1] = src[1];
        bfr[ni] = u.v;
      }
#pragma unroll
      for (int mi = 0; mi < 3; ++mi)
#pragma unroll
        for (int ni = 0; ni < 4; ++ni)
          acc[mi][ni] = __builtin_amdgcn_mfma_f32_16x16x32_bf16(a[mi], bfr[ni], acc[mi][ni], 0, 0, 0);
    }
  }
  // epilogue: LeakyReLU + residual RMW.  D: row(co)=quad*4+r, col(pixel)=col16
#pragma unroll
  for (int mi = 0; mi < 3; ++mi) {
#pragma unroll
    for (int ni = 0; ni < 4; ++ni) {
#pragma unroll
      for (int r = 0; r < 4; ++r) {
        int co = (wave * 3 + mi) * 16 + quad * 4 + r;
        size_t off = (((size_t)b * C_ + co) * H_ + (h0 + ni)) * W_ + w0 + col16;
        float v = acc[mi][ni][r];
        v = (v >= 0.f) ? v : 0.1f * v;
        out[off] = out[off] + v;
      }
    }
  }
}

// ---------------------------------------------------------------------------
extern "C" void kernel_launch(void* const* d_in, const int* in_sizes, int n_in,
                              void* d_out, int out_size, void* d_ws, size_t ws_size,
                              hipStream_t stream) {
  const float* x      = (const float*)d_in[0];
  const float* ln_w   = (const float*)d_in[1];
  const float* qkv_w  = (const float*)d_in[2];
  const float* qkv_b  = (const float*)d_in[3];
  const float* proj_w = (const float*)d_in[4];
  const float* proj_b = (const float*)d_in[5];
  const float* b1_w   = (const float*)d_in[6];
  const float* b1_b   = (const float*)d_in[7];
  const float* b2_w   = (const float*)d_in[8];
  const float* b2_b   = (const float*)d_in[9];
  const float* cw1    = (const float*)d_in[10];
  const float* cb1    = (const float*)d_in[11];
  const float* cw2    = (const float*)d_in[12];
  const float* cb2    = (const float*)d_in[13];
  const int*   bidx   = (const int*)d_in[14];
  const float* bdelta = (const float*)d_in[15];
  float* out = (float*)d_out;

  char* ws = (char*)d_ws;
  float* bias = (float*)ws;                         // 4096 f32 (16384 B)
  bf16*  wpk  = (bf16*)(ws + 16384);                // 9*192*192 bf16 (663552 B)
  bf16*  big  = (bf16*)(ws + 16384 + 663552);       // qkv (ci-major) then y (ch-last)

  hipLaunchKernelGGL(k_prep, dim3(1296), dim3(256), 0, stream,
                     b1_w, b1_b, b2_w, b2_b, bidx, bdelta, cw2, bias, wpk);
  hipLaunchKernelGGL(k_ln_qkv, dim3(4608), dim3(256), 0, stream,
                     x, ln_w, qkv_w, qkv_b, big);
  hipLaunchKernelGGL(k_attn, dim3(4608), dim3(256), 0, stream,
                     big, bias, proj_w, proj_b, x, out);
  hipLaunchKernelGGL(k_conv1_glu, dim3(4608), dim3(256), 0, stream,
                     out, cw1, cb1, big);
  hipLaunchKernelGGL(k_conv2, dim3(4608), dim3(256), 0, stream,
                     big, wpk, cb2, out);
}

// Round 2
// 2053.023 us; speedup vs baseline: 2.6125x; 1.5285x over previous
//
#include <hip/hip_runtime.h>
#include <hip/hip_bf16.h>
#include <math.h>

#define B_ 8
#define C_ 192
#define H_ 192
#define W_ 192
#define NWH 24   // windows per spatial dim

typedef __hip_bfloat16 bf16;
typedef short bf16x8 __attribute__((ext_vector_type(8)));
typedef short bf16x4 __attribute__((ext_vector_type(4)));
typedef float f32x4 __attribute__((ext_vector_type(4)));

__device__ __forceinline__ float bf2f(bf16 v) { return __bfloat162float(v); }
__device__ __forceinline__ bf16 f2bf(float v) { return __float2bfloat16(v); }

union bu { bf16 b; ushort u; };

// ---------------------------------------------------------------------------
// K0: bias MLP + gather (block 0), qkv rowsums (block 1),
//     cw2 repack to bf16 [tap][co][ci] (all blocks)
// ---------------------------------------------------------------------------
__global__ __launch_bounds__(256) void k_prep(
    const float* __restrict__ b1_w, const float* __restrict__ b1_b,
    const float* __restrict__ b2_w, const float* __restrict__ b2_b,
    const int* __restrict__ bias_index, const float* __restrict__ bias_delta,
    const float* __restrict__ cw2,
    const float* __restrict__ ln_w, const float* __restrict__ qkv_w,
    float* __restrict__ bias_out, bf16* __restrict__ wpk,
    float* __restrict__ rowsum) {
  int t = threadIdx.x;
  if (blockIdx.x == 0) {
    __shared__ float val[256];
    if (t < 225) {
      float dy = bias_delta[2 * t], dx = bias_delta[2 * t + 1];
      float acc = b2_b[0];
      for (int j = 0; j < 16; ++j) {
        float hj = b1_w[2 * j] * dy + b1_w[2 * j + 1] * dx + b1_b[j];
        float g = 0.5f * hj * (1.0f + erff(hj * 0.7071067811865475f));  // exact GELU
        acc += g * b2_w[j];
      }
      val[t] = acc;
    }
    __syncthreads();
    for (int i = t; i < 4096; i += 256) {
      int idx = bias_index[i];
      idx = min(max(idx, 0), 224);
      bias_out[i] = val[idx];
    }
  }
  if (blockIdx.x == 1 && t < 192) {
    // rowsum[j] = sum_c qkv_w[j][c] * ln_w[c]   (for LN mean folding)
    float s = 0.f;
    for (int c = 0; c < C_; ++c) s += qkv_w[t * C_ + c] * ln_w[c];
    rowsum[t] = s;
  }
  // repack cw2 [co][ci][9] -> bf16 wpk[tap][co][ci]
  int idx = blockIdx.x * 256 + t;
  if (idx < 9 * 192 * 192) {
    int tp = idx / 36864;
    int r = idx % 36864;
    int co = r / 192, ci = r % 192;
    wpk[idx] = f2bf(cw2[(co * 192 + ci) * 9 + tp]);
  }
}

// ---------------------------------------------------------------------------
// K1: per-pixel LayerNorm over C + QKV GEMM as MFMA implicit GEMM.
// Linearity trick: W·((x-mu)/sig*g) = (1/sig)·(W·(g*x) - mu·rowsum).
// Staging pass accumulates fp32 mean/var while writing bf16(g*x) to LDS.
// M=192 qkv outputs, N=64 pixels, K=192.  Wave w owns channels [48w,48w+48).
// ---------------------------------------------------------------------------
__global__ __launch_bounds__(256) void k_ln_qkv(
    const float* __restrict__ x, const float* __restrict__ ln_w,
    const float* __restrict__ qkv_w, const float* __restrict__ qkv_b,
    const float* __restrict__ rowsum, bf16* __restrict__ qkv) {
  __shared__ ushort xs[64 * 204];   // bf16 (g*x), [pixel][ci], stride 204
  __shared__ float red[512];
  __shared__ float mus[64], rsigs[64];
  int t = threadIdx.x;
  int blk = blockIdx.x;
  int b = blk / (H_ * 3);
  int rem = blk % (H_ * 3);
  int h = rem / 3;
  int w0 = (rem % 3) * 64;
  int p = t & 63, q = t >> 6;
  const float* xb = x + ((size_t)b * C_ * H_ + h) * W_ + w0;
  float s = 0.f, s2 = 0.f;
  for (int c = q; c < C_; c += 4) {
    float v = xb[(size_t)c * H_ * W_ + p];
    s += v; s2 += v * v;
    bu cv; cv.b = f2bf(v * ln_w[c]);
    xs[p * 204 + c] = cv.u;
  }
  red[q * 64 + p] = s;
  red[256 + q * 64 + p] = s2;
  __syncthreads();
  if (t < 64) {
    float su = red[t] + red[64 + t] + red[128 + t] + red[192 + t];
    float su2 = red[256 + t] + red[320 + t] + red[384 + t] + red[448 + t];
    float mu = su * (1.f / 192.f);
    float m2 = su2 * (1.f / 192.f);
    mus[t] = mu;
    rsigs[t] = rsqrtf(m2 - mu * mu + 1e-5f);
  }
  __syncthreads();

  int wave = t >> 6, lane = t & 63;
  int col16 = lane & 15, quad = lane >> 4;
  f32x4 acc[3][4];
#pragma unroll
  for (int mi = 0; mi < 3; ++mi)
#pragma unroll
    for (int ni = 0; ni < 4; ++ni)
#pragma unroll
      for (int r = 0; r < 4; ++r) acc[mi][ni][r] = 0.f;

  for (int ksi = 0; ksi < 6; ++ksi) {
    bf16x8 bfr[4];
#pragma unroll
    for (int ni = 0; ni < 4; ++ni) {
      const bf16x4* src =
          (const bf16x4*)(&xs[(ni * 16 + col16) * 204 + ksi * 32 + quad * 8]);
      union { bf16x8 v; bf16x4 h[2]; } u;
      u.h[0] = src[0];
      u.h[1] = src[1];
      bfr[ni] = u.v;
    }
#pragma unroll
    for (int mi = 0; mi < 3; ++mi) {
      int co = wave * 48 + mi * 16 + col16;
      const float* wsrc = qkv_w + (size_t)co * 192 + ksi * 32 + quad * 8;
      float4 wa = *(const float4*)(wsrc);
      float4 wb = *(const float4*)(wsrc + 4);
      bf16x8 a;
      {
        bu cv;
        cv.b = f2bf(wa.x); a[0] = (short)cv.u;
        cv.b = f2bf(wa.y); a[1] = (short)cv.u;
        cv.b = f2bf(wa.z); a[2] = (short)cv.u;
        cv.b = f2bf(wa.w); a[3] = (short)cv.u;
        cv.b = f2bf(wb.x); a[4] = (short)cv.u;
        cv.b = f2bf(wb.y); a[5] = (short)cv.u;
        cv.b = f2bf(wb.z); a[6] = (short)cv.u;
        cv.b = f2bf(wb.w); a[7] = (short)cv.u;
      }
#pragma unroll
      for (int ni = 0; ni < 4; ++ni)
        acc[mi][ni] =
            __builtin_amdgcn_mfma_f32_16x16x32_bf16(a, bfr[ni], acc[mi][ni], 0, 0, 0);
    }
  }

  // epilogue: qkv = rsig*(acc - mu*rowsum) + b.  D: row(co)=quad*4+r, col(px)=col16
  bf16* ob = qkv + ((size_t)b * C_ * H_ + h) * W_ + w0;
#pragma unroll
  for (int mi = 0; mi < 3; ++mi) {
    int cob = wave * 48 + mi * 16 + quad * 4;
#pragma unroll
    for (int r = 0; r < 4; ++r) {
      int co = cob + r;
      float rs = rowsum[co];
      float bv = qkv_b[co];
#pragma unroll
      for (int ni = 0; ni < 4; ++ni) {
        int px = ni * 16 + col16;
        float v = rsigs[px] * (acc[mi][ni][r] - mus[px] * rs) + bv;
        ob[(size_t)co * H_ * W_ + px] = f2bf(v);
      }
    }
  }
}

// ---------------------------------------------------------------------------
// K2: windowed attention + proj + residual.  Block = one 8x8 window.
// ---------------------------------------------------------------------------
__global__ __launch_bounds__(256) void k_attn(
    const bf16* __restrict__ qkv, const float* __restrict__ bias,
    const float* __restrict__ proj_w, const float* __restrict__ proj_b,
    const float* __restrict__ x, float* __restrict__ out) {
  __shared__ float qs[64 * 17], ks[64 * 17], vs[64 * 17];
  __shared__ float ss[64 * 67];
  __shared__ float os[64 * 65];
  int t = threadIdx.x;
  int blk = blockIdx.x;
  int b = blk / (NWH * NWH);
  int rem = blk % (NWH * NWH);
  int wh = rem / NWH, ww = rem % NWH;
  int h0 = wh * 8, w0 = ww * 8;
  size_t base = ((size_t)b * C_ * H_ + h0) * W_ + w0;
  int p = t & 63, g = t >> 6;

  for (int hd = 0; hd < 4; ++hd) {
    for (int k = 0; k < 4; ++k) {
      int e = k * 256 + t;
      int pp = e & 63, j = e >> 6;
      int i = pp >> 3, jj = pp & 7;
      size_t off = base + (size_t)i * W_ + jj;
      qs[pp * 17 + j] = bf2f(qkv[off + (size_t)(hd * 16 + j) * H_ * W_]);
      ks[pp * 17 + j] = bf2f(qkv[off + (size_t)(64 + hd * 16 + j) * H_ * W_]);
      vs[pp * 17 + j] = bf2f(qkv[off + (size_t)(128 + hd * 16 + j) * H_ * W_]);
    }
    __syncthreads();
    float qv[16];
#pragma unroll
    for (int j = 0; j < 16; ++j) qv[j] = qs[p * 17 + j];
    for (int mm = 0; mm < 16; ++mm) {
      int m = g * 16 + mm;
      float sc = 0.f;
#pragma unroll
      for (int j = 0; j < 16; ++j) sc += qv[j] * ks[m * 17 + j];
      ss[p * 67 + m] = sc * 0.25f + bias[p * 64 + m];
    }
    __syncthreads();
    if (t < 64) {
      float mx = -1e30f;
      for (int m = 0; m < 64; ++m) mx = fmaxf(mx, ss[t * 67 + m]);
      float sum = 0.f;
      for (int m = 0; m < 64; ++m) {
        float e_ = __expf(ss[t * 67 + m] - mx);
        ss[t * 67 + m] = e_; sum += e_;
      }
      float inv = 1.f / sum;
      for (int m = 0; m < 64; ++m) ss[t * 67 + m] *= inv;
    }
    __syncthreads();
    float oa[4] = {0.f, 0.f, 0.f, 0.f};
    for (int m = 0; m < 64; ++m) {
      float sv = ss[p * 67 + m];
#pragma unroll
      for (int jj = 0; jj < 4; ++jj) oa[jj] += sv * vs[m * 17 + g * 4 + jj];
    }
#pragma unroll
    for (int jj = 0; jj < 4; ++jj) os[p * 65 + hd * 16 + g * 4 + jj] = oa[jj];
    __syncthreads();
  }
  float acc[48];
#pragma unroll
  for (int j = 0; j < 48; ++j) acc[j] = proj_b[g * 48 + j];
  for (int m = 0; m < 64; m += 4) {
    float o0 = os[p * 65 + m], o1 = os[p * 65 + m + 1];
    float o2 = os[p * 65 + m + 2], o3 = os[p * 65 + m + 3];
    const float* wb = proj_w + (g * 48) * 64 + m;
#pragma unroll
    for (int j = 0; j < 48; ++j) {
      float4 w4 = *(const float4*)(wb + j * 64);
      acc[j] = fmaf(o0, w4.x, fmaf(o1, w4.y, fmaf(o2, w4.z, fmaf(o3, w4.w, acc[j]))));
    }
  }
  int i = p >> 3, jj = p & 7;
  size_t pb = base + (size_t)i * W_ + jj;
#pragma unroll
  for (int j = 0; j < 48; ++j) {
    size_t off = pb + (size_t)(g * 48 + j) * H_ * W_;
    out[off] = acc[j] + x[off];
  }
}

// ---------------------------------------------------------------------------
// K3: 1x1 conv (C->2C) + GLU as implicit GEMM on MFMA.
// M=384 out-ch, N=64 pixels (one h row, 64-wide w tile), K=192.
// Block = 256 thr (4 waves).  Wave w owns a-channels [w*48,w*48+48) (3 m-tiles)
// and the matching g-channels +192 (3 m-tiles) so GLU pairing is wave-local.
// Weights converted fp32->bf16 in-register (broadcast loads, L2-resident).
// Output y is CHANNELS-LAST bf16: y[((b*H+h)*W+w)*192 + c]  (for conv2 MFMA)
// ---------------------------------------------------------------------------
__global__ __launch_bounds__(256) void k_conv1_glu(
    const float* __restrict__ xa, const float* __restrict__ cw1,
    const float* __restrict__ cb1, bf16* __restrict__ y) {
  __shared__ ushort xs[64 * 204];   // bf16 [pixel][ci], stride 204 (2-way alias max)
  int t = threadIdx.x;
  int blk = blockIdx.x;
  int b = blk / (H_ * 3);
  int rem = blk % (H_ * 3);
  int h = rem / 3;
  int w0 = (rem % 3) * 64;
  int p = t & 63, q = t >> 6;
  const float* xb = xa + ((size_t)b * C_ * H_ + h) * W_ + w0;
  for (int c = q; c < C_; c += 4) {
    bu cv; cv.b = f2bf(xb[(size_t)c * H_ * W_ + p]);
    xs[p * 204 + c] = cv.u;
  }
  __syncthreads();

  int wave = t >> 6, lane = t & 63;
  int col16 = lane & 15, quad = lane >> 4;
  // acc[mi]: mi 0..2 -> a channels (co = wave*48 + mi*16), mi 3..5 -> g (+192)
  f32x4 acc[6][4];
#pragma unroll
  for (int mi = 0; mi < 6; ++mi) {
    int cob = (mi < 3) ? wave * 48 + mi * 16 : 192 + wave * 48 + (mi - 3) * 16;
#pragma unroll
    for (int r = 0; r < 4; ++r) {
      float bv = cb1[cob + quad * 4 + r];
#pragma unroll
      for (int ni = 0; ni < 4; ++ni) acc[mi][ni][r] = bv;
    }
  }

  for (int ksi = 0; ksi < 6; ++ksi) {
    // B fragments: 4 n-tiles of 16 pixels, k = ksi*32 + quad*8 .. +8
    bf16x8 bfr[4];
#pragma unroll
    for (int ni = 0; ni < 4; ++ni) {
      const bf16x4* src =
          (const bf16x4*)(&xs[(ni * 16 + col16) * 204 + ksi * 32 + quad * 8]);
      union { bf16x8 v; bf16x4 h[2]; } u;
      u.h[0] = src[0];
      u.h[1] = src[1];
      bfr[ni] = u.v;
    }
#pragma unroll
    for (int mi = 0; mi < 6; ++mi) {
      int cob = (mi < 3) ? wave * 48 + mi * 16 : 192 + wave * 48 + (mi - 3) * 16;
      const float* wsrc = cw1 + (size_t)(cob + col16) * 192 + ksi * 32 + quad * 8;
      float4 wa = *(const float4*)(wsrc);
      float4 wb = *(const float4*)(wsrc + 4);
      bf16x8 a;
      {
        bu cv;
        cv.b = f2bf(wa.x); a[0] = (short)cv.u;
        cv.b = f2bf(wa.y); a[1] = (short)cv.u;
        cv.b = f2bf(wa.z); a[2] = (short)cv.u;
        cv.b = f2bf(wa.w); a[3] = (short)cv.u;
        cv.b = f2bf(wb.x); a[4] = (short)cv.u;
        cv.b = f2bf(wb.y); a[5] = (short)cv.u;
        cv.b = f2bf(wb.z); a[6] = (short)cv.u;
        cv.b = f2bf(wb.w); a[7] = (short)cv.u;
      }
#pragma unroll
      for (int ni = 0; ni < 4; ++ni)
        acc[mi][ni] =
            __builtin_amdgcn_mfma_f32_16x16x32_bf16(a, bfr[ni], acc[mi][ni], 0, 0, 0);
    }
  }
  __syncthreads();   // all xs reads done; reuse xs for output staging

  // GLU epilogue: res = a * sigmoid(g).  D layout: row(co)=quad*4+r, col(px)=col16
#pragma unroll
  for (int mi = 0; mi < 3; ++mi) {
#pragma unroll
    for (int ni = 0; ni < 4; ++ni) {
      int px = ni * 16 + col16;
      int co = wave * 48 + mi * 16 + quad * 4;
#pragma unroll
      for (int rr = 0; rr < 2; ++rr) {
        float a0 = acc[mi][ni][rr * 2], a1 = acc[mi][ni][rr * 2 + 1];
        float g0 = acc[mi + 3][ni][rr * 2], g1 = acc[mi + 3][ni][rr * 2 + 1];
        float r0 = a0 / (1.f + __expf(-g0));
        float r1 = a1 / (1.f + __expf(-g1));
        bu c0, c1;
        c0.b = f2bf(r0); c1.b = f2bf(r1);
        *(uint*)(&xs[px * 204 + co + rr * 2]) = (uint)c0.u | ((uint)c1.u << 16);
      }
    }
  }
  __syncthreads();
  // coalesced channels-last store: 64 px x 24 chunks of 8 bf16
  ushort* yb = (ushort*)y + (((size_t)b * H_ + h) * W_ + w0) * 192;
#pragma unroll
  for (int i = 0; i < 6; ++i) {
    int e = i * 256 + t;
    int px = e / 24, ch = e % 24;
    uint u0 = *(const uint*)(&xs[px * 204 + ch * 8]);
    uint u1 = *(const uint*)(&xs[px * 204 + ch * 8 + 2]);
    uint u2 = *(const uint*)(&xs[px * 204 + ch * 8 + 4]);
    uint u3 = *(const uint*)(&xs[px * 204 + ch * 8 + 6]);
    uint4 pk; pk.x = u0; pk.y = u1; pk.z = u2; pk.w = u3;
    *(uint4*)(yb + (size_t)px * 192 + ch * 8) = pk;
  }
}

// ---------------------------------------------------------------------------
// K4: 3x3 conv as implicit GEMM on MFMA.  M=192 out-ch, N=64 pixels (4 rows x
// 16 cols), K=9*192.  Block = 256 thr (4 waves); wave w: m-tiles {3w..3w+2},
// all 4 n-tiles.  LDS: halo tile channels-last, pad 204 (<=2-way bank alias).
// ---------------------------------------------------------------------------
__global__ __launch_bounds__(256) void k_conv2(
    const bf16* __restrict__ y, const bf16* __restrict__ wpk,
    const float* __restrict__ cb2, float* __restrict__ out) {
  __shared__ ushort yl[6 * 18 * 204];  // [halo pixel][ci], 44064 B
  int t = threadIdx.x;
  int blk = blockIdx.x;
  int b = blk / (48 * 12);
  int rem = blk % (48 * 12);
  int h0 = (rem / 12) * 4;
  int w0 = (rem % 12) * 16;
  // stage 108 halo pixels x 192 ci (8B chunks, replicate-clamped)
  const ushort* yg = (const ushort*)y;
  for (int e = t; e < 108 * 48; e += 256) {
    int p = e / 48, c8 = e % 48;
    int prow = p / 18, pcol = p % 18;
    int gr = min(max(h0 - 1 + prow, 0), H_ - 1);
    int gc = min(max(w0 - 1 + pcol, 0), W_ - 1);
    *(float2*)(&yl[p * 204 + c8 * 4]) =
        *(const float2*)(yg + (((size_t)b * H_ + gr) * W_ + gc) * 192 + c8 * 4);
  }
  __syncthreads();
  int wave = t >> 6, lane = t & 63;
  int col16 = lane & 15, quad = lane >> 4;
  f32x4 acc[3][4];
#pragma unroll
  for (int mi = 0; mi < 3; ++mi) {
#pragma unroll
    for (int r = 0; r < 4; ++r) {
      float bv = cb2[(wave * 3 + mi) * 16 + quad * 4 + r];
#pragma unroll
      for (int ni = 0; ni < 4; ++ni) acc[mi][ni][r] = bv;
    }
  }
  const ushort* wq = (const ushort*)wpk;
  for (int tap = 0; tap < 9; ++tap) {
    int dy = tap / 3, dx = tap % 3;
#pragma unroll
    for (int ks = 0; ks < 6; ++ks) {
      bf16x8 a[3];
#pragma unroll
      for (int mi = 0; mi < 3; ++mi) {
        int co = (wave * 3 + mi) * 16 + col16;
        a[mi] = *(const bf16x8*)(wq + ((size_t)tap * 192 + co) * 192 + ks * 32 + quad * 8);
      }
      bf16x8 bfr[4];
#pragma unroll
      for (int ni = 0; ni < 4; ++ni) {
        int p = (ni + dy) * 18 + col16 + dx;
        const bf16x4* src = (const bf16x4*)(&yl[p * 204 + ks * 32 + quad * 8]);
        union { bf16x8 v; bf16x4 h[2]; } u;
        u.h[0] = src[0];
        u.h[1] = src[1];
        bfr[ni] = u.v;
      }
#pragma unroll
      for (int mi = 0; mi < 3; ++mi)
#pragma unroll
        for (int ni = 0; ni < 4; ++ni)
          acc[mi][ni] = __builtin_amdgcn_mfma_f32_16x16x32_bf16(a[mi], bfr[ni], acc[mi][ni], 0, 0, 0);
    }
  }
  // epilogue: LeakyReLU + residual RMW.  D: row(co)=quad*4+r, col(pixel)=col16
#pragma unroll
  for (int mi = 0; mi < 3; ++mi) {
#pragma unroll
    for (int ni = 0; ni < 4; ++ni) {
#pragma unroll
      for (int r = 0; r < 4; ++r) {
        int co = (wave * 3 + mi) * 16 + quad * 4 + r;
        size_t off = (((size_t)b * C_ + co) * H_ + (h0 + ni)) * W_ + w0 + col16;
        float v = acc[mi][ni][r];
        v = (v >= 0.f) ? v : 0.1f * v;
        out[off] = out[off] + v;
      }
    }
  }
}

// ---------------------------------------------------------------------------
extern "C" void kernel_launch(void* const* d_in, const int* in_sizes, int n_in,
                              void* d_out, int out_size, void* d_ws, size_t ws_size,
                              hipStream_t stream) {
  const float* x      = (const float*)d_in[0];
  const float* ln_w   = (const float*)d_in[1];
  const float* qkv_w  = (const float*)d_in[2];
  const float* qkv_b  = (const float*)d_in[3];
  const float* proj_w = (const float*)d_in[4];
  const float* proj_b = (const float*)d_in[5];
  const float* b1_w   = (const float*)d_in[6];
  const float* b1_b   = (const float*)d_in[7];
  const float* b2_w   = (const float*)d_in[8];
  const float* b2_b   = (const float*)d_in[9];
  const float* cw1    = (const float*)d_in[10];
  const float* cb1    = (const float*)d_in[11];
  const float* cw2    = (const float*)d_in[12];
  const float* cb2    = (const float*)d_in[13];
  const int*   bidx   = (const int*)d_in[14];
  const float* bdelta = (const float*)d_in[15];
  float* out = (float*)d_out;

  char* ws = (char*)d_ws;
  float* bias   = (float*)ws;                        // 4096 f32 (16384 B)
  bf16*  wpk    = (bf16*)(ws + 16384);               // 9*192*192 bf16 (663552 B)
  float* rowsum = (float*)(ws + 16384 + 663552);     // 192 f32 (pad to 1024 B)
  bf16*  big    = (bf16*)(ws + 16384 + 663552 + 1024); // qkv (ci-major) then y (ch-last)

  hipLaunchKernelGGL(k_prep, dim3(1296), dim3(256), 0, stream,
                     b1_w, b1_b, b2_w, b2_b, bidx, bdelta, cw2, ln_w, qkv_w,
                     bias, wpk, rowsum);
  hipLaunchKernelGGL(k_ln_qkv, dim3(4608), dim3(256), 0, stream,
                     x, ln_w, qkv_w, qkv_b, rowsum, big);
  hipLaunchKernelGGL(k_attn, dim3(4608), dim3(256), 0, stream,
                     big, bias, proj_w, proj_b, x, out);
  hipLaunchKernelGGL(k_conv1_glu, dim3(4608), dim3(256), 0, stream,
                     out, cw1, cb1, big);
  hipLaunchKernelGGL(k_conv2, dim3(4608), dim3(256), 0, stream,
                     big, wpk, cb2, out);
}

// Round 3
// 1535.295 us; speedup vs baseline: 3.4935x; 1.3372x over previous
//
#include <hip/hip_runtime.h>
#include <hip/hip_bf16.h>
#include <math.h>

#define B_ 8
#define C_ 192
#define H_ 192
#define W_ 192
#define NWH 24   // windows per spatial dim

typedef __hip_bfloat16 bf16;
typedef short bf16x8 __attribute__((ext_vector_type(8)));
typedef short bf16x4 __attribute__((ext_vector_type(4)));
typedef float f32x4 __attribute__((ext_vector_type(4)));
typedef float f32x16 __attribute__((ext_vector_type(16)));

__device__ __forceinline__ float bf2f(bf16 v) { return __bfloat162float(v); }
__device__ __forceinline__ bf16 f2bf(float v) { return __float2bfloat16(v); }

union bu { bf16 b; ushort u; };

__device__ __forceinline__ uint packbf2(float a, float b) {
  bu c0, c1; c0.b = f2bf(a); c1.b = f2bf(b);
  return (uint)c0.u | ((uint)c1.u << 16);
}

// ---------------------------------------------------------------------------
// K0: bias MLP + gather -> MFMA-register-layout packed bias (block 0),
//     qkv rowsums (block 1), cw2 repack to bf16 [tap][co][ci] (all blocks)
// bias_pk[((nt*2+m)*16+reg)*64 + (q&31) + 32*hi] = bias[q][k] where
// k = m*32 + (reg&3) + 8*(reg>>2) + 4*hi,  q = nt*32 + (q&31).
// ---------------------------------------------------------------------------
__global__ __launch_bounds__(256) void k_prep(
    const float* __restrict__ b1_w, const float* __restrict__ b1_b,
    const float* __restrict__ b2_w, const float* __restrict__ b2_b,
    const int* __restrict__ bias_index, const float* __restrict__ bias_delta,
    const float* __restrict__ cw2,
    const float* __restrict__ ln_w, const float* __restrict__ qkv_w,
    float* __restrict__ bias_pk, bf16* __restrict__ wpk,
    float* __restrict__ rowsum) {
  int t = threadIdx.x;
  if (blockIdx.x == 0) {
    __shared__ float val[256];
    if (t < 225) {
      float dy = bias_delta[2 * t], dx = bias_delta[2 * t + 1];
      float acc = b2_b[0];
      for (int j = 0; j < 16; ++j) {
        float hj = b1_w[2 * j] * dy + b1_w[2 * j + 1] * dx + b1_b[j];
        float g = 0.5f * hj * (1.0f + erff(hj * 0.7071067811865475f));  // exact GELU
        acc += g * b2_w[j];
      }
      val[t] = acc;
    }
    __syncthreads();
    for (int i = t; i < 4096; i += 256) {
      int idx = bias_index[i];
      idx = min(max(idx, 0), 224);
      float v = val[idx];
      int q = i >> 6, k = i & 63;
      int nt = q >> 5, m = k >> 5, kl = k & 31;
      int hi2 = (kl >> 2) & 1, reg = (kl & 3) + 4 * (kl >> 3);
      bias_pk[((nt * 2 + m) * 16 + reg) * 64 + (q & 31) + 32 * hi2] = v;
    }
  }
  if (blockIdx.x == 1 && t < 192) {
    // rowsum[j] = sum_c qkv_w[j][c] * ln_w[c]   (for LN mean folding)
    float s = 0.f;
    for (int c = 0; c < C_; ++c) s += qkv_w[t * C_ + c] * ln_w[c];
    rowsum[t] = s;
  }
  // repack cw2 [co][ci][9] -> bf16 wpk[tap][co][ci]
  int idx = blockIdx.x * 256 + t;
  if (idx < 9 * 192 * 192) {
    int tp = idx / 36864;
    int r = idx % 36864;
    int co = r / 192, ci = r % 192;
    wpk[idx] = f2bf(cw2[(co * 192 + ci) * 9 + tp]);
  }
}

// ---------------------------------------------------------------------------
// K1: per-pixel LayerNorm over C + QKV GEMM as MFMA implicit GEMM.
// Linearity trick: W·((x-mu)/sig*g) = (1/sig)·(W·(g*x) - mu·rowsum).
// Output layout: WINDOW-CONTIGUOUS qkv[win][192ch][64px] bf16, where
// win = (b*24 + h/8)*24 + w/8, px = (h%8)*8 + (w%8).
// ---------------------------------------------------------------------------
__global__ __launch_bounds__(256) void k_ln_qkv(
    const float* __restrict__ x, const float* __restrict__ ln_w,
    const float* __restrict__ qkv_w, const float* __restrict__ qkv_b,
    const float* __restrict__ rowsum, bf16* __restrict__ qkv) {
  __shared__ ushort xs[64 * 204];   // bf16 (g*x), [pixel][ci], stride 204
  __shared__ float red[512];
  __shared__ float mus[64], rsigs[64];
  int t = threadIdx.x;
  int blk = blockIdx.x;
  int b = blk / (H_ * 3);
  int rem = blk % (H_ * 3);
  int h = rem / 3;
  int w0 = (rem % 3) * 64;
  int p = t & 63, q = t >> 6;
  const float* xb = x + ((size_t)b * C_ * H_ + h) * W_ + w0;
  float s = 0.f, s2 = 0.f;
  for (int c = q; c < C_; c += 4) {
    float v = xb[(size_t)c * H_ * W_ + p];
    s += v; s2 += v * v;
    bu cv; cv.b = f2bf(v * ln_w[c]);
    xs[p * 204 + c] = cv.u;
  }
  red[q * 64 + p] = s;
  red[256 + q * 64 + p] = s2;
  __syncthreads();
  if (t < 64) {
    float su = red[t] + red[64 + t] + red[128 + t] + red[192 + t];
    float su2 = red[256 + t] + red[320 + t] + red[384 + t] + red[448 + t];
    float mu = su * (1.f / 192.f);
    float m2 = su2 * (1.f / 192.f);
    mus[t] = mu;
    rsigs[t] = rsqrtf(m2 - mu * mu + 1e-5f);
  }
  __syncthreads();

  int wave = t >> 6, lane = t & 63;
  int col16 = lane & 15, quad = lane >> 4;
  f32x4 acc[3][4];
#pragma unroll
  for (int mi = 0; mi < 3; ++mi)
#pragma unroll
    for (int ni = 0; ni < 4; ++ni)
#pragma unroll
      for (int r = 0; r < 4; ++r) acc[mi][ni][r] = 0.f;

  for (int ksi = 0; ksi < 6; ++ksi) {
    bf16x8 bfr[4];
#pragma unroll
    for (int ni = 0; ni < 4; ++ni) {
      const bf16x4* src =
          (const bf16x4*)(&xs[(ni * 16 + col16) * 204 + ksi * 32 + quad * 8]);
      union { bf16x8 v; bf16x4 h[2]; } u;
      u.h[0] = src[0];
      u.h[1] = src[1];
      bfr[ni] = u.v;
    }
#pragma unroll
    for (int mi = 0; mi < 3; ++mi) {
      int co = wave * 48 + mi * 16 + col16;
      const float* wsrc = qkv_w + (size_t)co * 192 + ksi * 32 + quad * 8;
      float4 wa = *(const float4*)(wsrc);
      float4 wb = *(const float4*)(wsrc + 4);
      bf16x8 a;
      {
        bu cv;
        cv.b = f2bf(wa.x); a[0] = (short)cv.u;
        cv.b = f2bf(wa.y); a[1] = (short)cv.u;
        cv.b = f2bf(wa.z); a[2] = (short)cv.u;
        cv.b = f2bf(wa.w); a[3] = (short)cv.u;
        cv.b = f2bf(wb.x); a[4] = (short)cv.u;
        cv.b = f2bf(wb.y); a[5] = (short)cv.u;
        cv.b = f2bf(wb.z); a[6] = (short)cv.u;
        cv.b = f2bf(wb.w); a[7] = (short)cv.u;
      }
#pragma unroll
      for (int ni = 0; ni < 4; ++ni)
        acc[mi][ni] =
            __builtin_amdgcn_mfma_f32_16x16x32_bf16(a, bfr[ni], acc[mi][ni], 0, 0, 0);
    }
  }

  // epilogue: qkv = rsig*(acc - mu*rowsum) + b  -> window layout
  size_t winbase = ((size_t)b * 24 + (h >> 3)) * 24 + (w0 >> 3);
  int hw8 = (h & 7) * 8;
  ushort* ob = (ushort*)qkv;
#pragma unroll
  for (int mi = 0; mi < 3; ++mi) {
    int cob = wave * 48 + mi * 16 + quad * 4;
#pragma unroll
    for (int r = 0; r < 4; ++r) {
      int co = cob + r;
      float rs = rowsum[co];
      float bv = qkv_b[co];
#pragma unroll
      for (int ni = 0; ni < 4; ++ni) {
        int px = ni * 16 + col16;
        float v = rsigs[px] * (acc[mi][ni][r] - mus[px] * rs) + bv;
        size_t off = ((winbase + (px >> 3)) * 192 + co) * 64 + hw8 + (px & 7);
        bu cv; cv.b = f2bf(v);
        ob[off] = cv.u;
      }
    }
  }
}

// ---------------------------------------------------------------------------
// K2: windowed attention, full MFMA.  Block = one 8x8 window, wave = head.
// S^T = K·Q^T via mfma_32x32x16 (swapped so softmax is lane-local);
// P kept in registers (bf16-packed), redistributed via shfl_xor(32) into
// PV A-fragments; O via LDS (aliased over dead Q/K region) -> proj MFMA.
// ---------------------------------------------------------------------------
__global__ __launch_bounds__(256) void k_attn(
    const bf16* __restrict__ qkv, const float* __restrict__ bias_pk,
    const float* __restrict__ proj_w, const float* __restrict__ proj_b,
    const float* __restrict__ x, float* __restrict__ out) {
  __shared__ ushort qkvL[192 * 68];   // [ch][px], 26112 B; rows 0..63 reused as os[px][ch]
  int t = threadIdx.x;
  int blk = blockIdx.x;
  int b = blk / (NWH * NWH);
  int rem = blk % (NWH * NWH);
  int wh = rem / NWH, ww = rem % NWH;
  int h0 = wh * 8, w0 = ww * 8;
  int lane = t & 63, hd = t >> 6;
  int l31 = lane & 31, hi = lane >> 5;
  int col16 = lane & 15, quad = lane >> 4;

  // ---- stage qkv window (fully coalesced 16B loads) ----
  const ushort* qg = (const ushort*)qkv + (size_t)blk * 12288;
#pragma unroll
  for (int i = 0; i < 6; ++i) {
    int e = i * 256 + t;
    int ch = e >> 3, chunk = e & 7;
    uint4 v = *(const uint4*)(qg + ch * 64 + chunk * 8);
    ushort* dst = &qkvL[ch * 68 + chunk * 8];
    *(uint2*)dst = make_uint2(v.x, v.y);
    *(uint2*)(dst + 4) = make_uint2(v.z, v.w);
  }
  __syncthreads();

  // ---- QK^T (swapped): S^T[key][q], 2x2 tiles of 32x32, K=16 ----
  bf16x8 ka[2], qb[2];
#pragma unroll
  for (int m = 0; m < 2; ++m) {
    union { bf16x8 v; ushort s[8]; } u;
#pragma unroll
    for (int j = 0; j < 8; ++j)
      u.s[j] = qkvL[(64 + hd * 16 + hi * 8 + j) * 68 + m * 32 + l31];
    ka[m] = u.v;
  }
#pragma unroll
  for (int n = 0; n < 2; ++n) {
    union { bf16x8 v; ushort s[8]; } u;
#pragma unroll
    for (int j = 0; j < 8; ++j)
      u.s[j] = qkvL[(hd * 16 + hi * 8 + j) * 68 + n * 32 + l31];
    qb[n] = u.v;
  }
  f32x16 accs[2][2];
#pragma unroll
  for (int m = 0; m < 2; ++m)
#pragma unroll
    for (int n = 0; n < 2; ++n) {
#pragma unroll
      for (int r = 0; r < 16; ++r) accs[m][n][r] = 0.f;
      accs[m][n] = __builtin_amdgcn_mfma_f32_32x32x16_bf16(ka[m], qb[n], accs[m][n], 0, 0, 0);
    }
  __syncthreads();   // all Q/K reads done (os will alias that region)

  // ---- softmax (lane-local + one shfl_xor(32)); P packed to bf16 pairs ----
  uint pk[2][2][8];
#pragma unroll
  for (int nt = 0; nt < 2; ++nt) {
    float sc[2][16];
#pragma unroll
    for (int m = 0; m < 2; ++m)
#pragma unroll
      for (int r = 0; r < 16; ++r)
        sc[m][r] = fmaf(accs[m][nt][r], 0.25f,
                        bias_pk[((nt * 2 + m) * 16 + r) * 64 + lane]);
    float m8[8];
#pragma unroll
    for (int r = 0; r < 8; ++r)
      m8[r] = fmaxf(fmaxf(sc[0][r], sc[0][r + 8]), fmaxf(sc[1][r], sc[1][r + 8]));
    float mx = fmaxf(fmaxf(fmaxf(m8[0], m8[1]), fmaxf(m8[2], m8[3])),
                     fmaxf(fmaxf(m8[4], m8[5]), fmaxf(m8[6], m8[7])));
    mx = fmaxf(mx, __shfl_xor(mx, 32));
    float s8[8];
#pragma unroll
    for (int r = 0; r < 8; ++r) {
      float e0 = __expf(sc[0][r] - mx);      sc[0][r] = e0;
      float e1 = __expf(sc[0][r + 8] - mx);  sc[0][r + 8] = e1;
      float e2 = __expf(sc[1][r] - mx);      sc[1][r] = e2;
      float e3 = __expf(sc[1][r + 8] - mx);  sc[1][r + 8] = e3;
      s8[r] = (e0 + e1) + (e2 + e3);
    }
    float sum = ((s8[0] + s8[1]) + (s8[2] + s8[3])) + ((s8[4] + s8[5]) + (s8[6] + s8[7]));
    sum += __shfl_xor(sum, 32);
    float inv = 1.f / sum;
#pragma unroll
    for (int m = 0; m < 2; ++m)
#pragma unroll
      for (int rp = 0; rp < 8; ++rp)
        pk[nt][m][rp] = packbf2(sc[m][2 * rp] * inv, sc[m][2 * rp + 1] * inv);
  }

  // ---- PV: O[q][d] = P·V, 2 m-tiles of 32x32, K=16 per step (4 steps) ----
  f32x16 acco[2];
#pragma unroll
  for (int mt = 0; mt < 2; ++mt) {
#pragma unroll
    for (int r = 0; r < 16; ++r) acco[mt][r] = 0.f;
    uint sw[2][8];
#pragma unroll
    for (int mb = 0; mb < 2; ++mb)
#pragma unroll
      for (int rp = 0; rp < 8; ++rp)
        sw[mb][rp] = __shfl_xor(pk[mt][mb][rp], 32);
#pragma unroll
    for (int kc = 0; kc < 4; ++kc) {
      int mb = kc >> 1, r0 = (kc & 1) * 4;
      union { bf16x8 v; uint d[4]; } af;
      af.d[0] = hi ? sw[mb][r0 + 2] : pk[mt][mb][r0 + 0];
      af.d[1] = hi ? sw[mb][r0 + 3] : pk[mt][mb][r0 + 1];
      af.d[2] = hi ? pk[mt][mb][r0 + 2] : sw[mb][r0 + 0];
      af.d[3] = hi ? pk[mt][mb][r0 + 3] : sw[mb][r0 + 1];
      union { bf16x8 v; uint2 h[2]; } bv;
      const ushort* vsrc = &qkvL[(128 + hd * 16 + col16) * 68 + kc * 16 + hi * 8];
      bv.h[0] = *(const uint2*)(vsrc);
      bv.h[1] = *(const uint2*)(vsrc + 4);
      acco[mt] = __builtin_amdgcn_mfma_f32_32x32x16_bf16(af.v, bv.v, acco[mt], 0, 0, 0);
    }
  }
  // ---- O -> os LDS (aliased over Q/K rows), layout os[px][68] ch-contig ----
  if (l31 < 16) {
#pragma unroll
    for (int mt = 0; mt < 2; ++mt)
#pragma unroll
      for (int r = 0; r < 16; ++r) {
        int qrow = mt * 32 + (r & 3) + 8 * (r >> 2) + 4 * hi;
        bu cv; cv.b = f2bf(acco[mt][r]);
        qkvL[qrow * 68 + hd * 16 + l31] = cv.u;
      }
  }
  __syncthreads();

  // ---- proj: M=192 co, N=64 px, K=64; wave hd owns co [48hd, 48hd+48) ----
  f32x4 accp[3][4];
#pragma unroll
  for (int mi = 0; mi < 3; ++mi)
#pragma unroll
    for (int r = 0; r < 4; ++r) {
      float bv = proj_b[hd * 48 + mi * 16 + quad * 4 + r];
#pragma unroll
      for (int ni = 0; ni < 4; ++ni) accp[mi][ni][r] = bv;
    }
#pragma unroll
  for (int kc = 0; kc < 2; ++kc) {
    bf16x8 bos[4];
#pragma unroll
    for (int ni = 0; ni < 4; ++ni) {
      const ushort* src = &qkvL[(ni * 16 + col16) * 68 + kc * 32 + quad * 8];
      union { bf16x8 v; uint2 h[2]; } u;
      u.h[0] = *(const uint2*)(src);
      u.h[1] = *(const uint2*)(src + 4);
      bos[ni] = u.v;
    }
#pragma unroll
    for (int mi = 0; mi < 3; ++mi) {
      const float* wsrc = proj_w + (size_t)(hd * 48 + mi * 16 + col16) * 64 + kc * 32 + quad * 8;
      float4 wa = *(const float4*)(wsrc);
      float4 wb = *(const float4*)(wsrc + 4);
      bf16x8 a;
      {
        bu cv;
        cv.b = f2bf(wa.x); a[0] = (short)cv.u;
        cv.b = f2bf(wa.y); a[1] = (short)cv.u;
        cv.b = f2bf(wa.z); a[2] = (short)cv.u;
        cv.b = f2bf(wa.w); a[3] = (short)cv.u;
        cv.b = f2bf(wb.x); a[4] = (short)cv.u;
        cv.b = f2bf(wb.y); a[5] = (short)cv.u;
        cv.b = f2bf(wb.z); a[6] = (short)cv.u;
        cv.b = f2bf(wb.w); a[7] = (short)cv.u;
      }
#pragma unroll
      for (int ni = 0; ni < 4; ++ni)
        accp[mi][ni] = __builtin_amdgcn_mfma_f32_16x16x32_bf16(a, bos[ni], accp[mi][ni], 0, 0, 0);
    }
  }
  // ---- residual add + store ----
  size_t base = ((size_t)b * C_ * H_ + h0) * W_ + w0;
#pragma unroll
  for (int mi = 0; mi < 3; ++mi) {
#pragma unroll
    for (int ni = 0; ni < 4; ++ni) {
#pragma unroll
      for (int r = 0; r < 4; ++r) {
        int co = hd * 48 + mi * 16 + quad * 4 + r;
        int px = ni * 16 + col16;
        size_t off = base + (size_t)co * H_ * W_ + (size_t)(px >> 3) * W_ + (px & 7);
        out[off] = accp[mi][ni][r] + x[off];
      }
    }
  }
}

// ---------------------------------------------------------------------------
// K3: 1x1 conv (C->2C) + GLU as implicit GEMM on MFMA.
// ---------------------------------------------------------------------------
__global__ __launch_bounds__(256) void k_conv1_glu(
    const float* __restrict__ xa, const float* __restrict__ cw1,
    const float* __restrict__ cb1, bf16* __restrict__ y) {
  __shared__ ushort xs[64 * 204];   // bf16 [pixel][ci], stride 204 (2-way alias max)
  int t = threadIdx.x;
  int blk = blockIdx.x;
  int b = blk / (H_ * 3);
  int rem = blk % (H_ * 3);
  int h = rem / 3;
  int w0 = (rem % 3) * 64;
  int p = t & 63, q = t >> 6;
  const float* xb = xa + ((size_t)b * C_ * H_ + h) * W_ + w0;
  for (int c = q; c < C_; c += 4) {
    bu cv; cv.b = f2bf(xb[(size_t)c * H_ * W_ + p]);
    xs[p * 204 + c] = cv.u;
  }
  __syncthreads();

  int wave = t >> 6, lane = t & 63;
  int col16 = lane & 15, quad = lane >> 4;
  f32x4 acc[6][4];
#pragma unroll
  for (int mi = 0; mi < 6; ++mi) {
    int cob = (mi < 3) ? wave * 48 + mi * 16 : 192 + wave * 48 + (mi - 3) * 16;
#pragma unroll
    for (int r = 0; r < 4; ++r) {
      float bv = cb1[cob + quad * 4 + r];
#pragma unroll
      for (int ni = 0; ni < 4; ++ni) acc[mi][ni][r] = bv;
    }
  }

  for (int ksi = 0; ksi < 6; ++ksi) {
    bf16x8 bfr[4];
#pragma unroll
    for (int ni = 0; ni < 4; ++ni) {
      const bf16x4* src =
          (const bf16x4*)(&xs[(ni * 16 + col16) * 204 + ksi * 32 + quad * 8]);
      union { bf16x8 v; bf16x4 h[2]; } u;
      u.h[0] = src[0];
      u.h[1] = src[1];
      bfr[ni] = u.v;
    }
#pragma unroll
    for (int mi = 0; mi < 6; ++mi) {
      int cob = (mi < 3) ? wave * 48 + mi * 16 : 192 + wave * 48 + (mi - 3) * 16;
      const float* wsrc = cw1 + (size_t)(cob + col16) * 192 + ksi * 32 + quad * 8;
      float4 wa = *(const float4*)(wsrc);
      float4 wb = *(const float4*)(wsrc + 4);
      bf16x8 a;
      {
        bu cv;
        cv.b = f2bf(wa.x); a[0] = (short)cv.u;
        cv.b = f2bf(wa.y); a[1] = (short)cv.u;
        cv.b = f2bf(wa.z); a[2] = (short)cv.u;
        cv.b = f2bf(wa.w); a[3] = (short)cv.u;
        cv.b = f2bf(wb.x); a[4] = (short)cv.u;
        cv.b = f2bf(wb.y); a[5] = (short)cv.u;
        cv.b = f2bf(wb.z); a[6] = (short)cv.u;
        cv.b = f2bf(wb.w); a[7] = (short)cv.u;
      }
#pragma unroll
      for (int ni = 0; ni < 4; ++ni)
        acc[mi][ni] =
            __builtin_amdgcn_mfma_f32_16x16x32_bf16(a, bfr[ni], acc[mi][ni], 0, 0, 0);
    }
  }
  __syncthreads();   // all xs reads done; reuse xs for output staging

#pragma unroll
  for (int mi = 0; mi < 3; ++mi) {
#pragma unroll
    for (int ni = 0; ni < 4; ++ni) {
      int px = ni * 16 + col16;
      int co = wave * 48 + mi * 16 + quad * 4;
#pragma unroll
      for (int rr = 0; rr < 2; ++rr) {
        float a0 = acc[mi][ni][rr * 2], a1 = acc[mi][ni][rr * 2 + 1];
        float g0 = acc[mi + 3][ni][rr * 2], g1 = acc[mi + 3][ni][rr * 2 + 1];
        float r0 = a0 / (1.f + __expf(-g0));
        float r1 = a1 / (1.f + __expf(-g1));
        bu c0, c1;
        c0.b = f2bf(r0); c1.b = f2bf(r1);
        *(uint*)(&xs[px * 204 + co + rr * 2]) = (uint)c0.u | ((uint)c1.u << 16);
      }
    }
  }
  __syncthreads();
  ushort* yb = (ushort*)y + (((size_t)b * H_ + h) * W_ + w0) * 192;
#pragma unroll
  for (int i = 0; i < 6; ++i) {
    int e = i * 256 + t;
    int px = e / 24, ch = e % 24;
    uint u0 = *(const uint*)(&xs[px * 204 + ch * 8]);
    uint u1 = *(const uint*)(&xs[px * 204 + ch * 8 + 2]);
    uint u2 = *(const uint*)(&xs[px * 204 + ch * 8 + 4]);
    uint u3 = *(const uint*)(&xs[px * 204 + ch * 8 + 6]);
    uint4 pkv; pkv.x = u0; pkv.y = u1; pkv.z = u2; pkv.w = u3;
    *(uint4*)(yb + (size_t)px * 192 + ch * 8) = pkv;
  }
}

// ---------------------------------------------------------------------------
// K4: 3x3 conv as implicit GEMM on MFMA.
// ---------------------------------------------------------------------------
__global__ __launch_bounds__(256) void k_conv2(
    const bf16* __restrict__ y, const bf16* __restrict__ wpk,
    const float* __restrict__ cb2, float* __restrict__ out) {
  __shared__ ushort yl[6 * 18 * 204];  // [halo pixel][ci], 44064 B
  int t = threadIdx.x;
  int blk = blockIdx.x;
  int b = blk / (48 * 12);
  int rem = blk % (48 * 12);
  int h0 = (rem / 12) * 4;
  int w0 = (rem % 12) * 16;
  const ushort* yg = (const ushort*)y;
  for (int e = t; e < 108 * 48; e += 256) {
    int p = e / 48, c8 = e % 48;
    int prow = p / 18, pcol = p % 18;
    int gr = min(max(h0 - 1 + prow, 0), H_ - 1);
    int gc = min(max(w0 - 1 + pcol, 0), W_ - 1);
    *(float2*)(&yl[p * 204 + c8 * 4]) =
        *(const float2*)(yg + (((size_t)b * H_ + gr) * W_ + gc) * 192 + c8 * 4);
  }
  __syncthreads();
  int wave = t >> 6, lane = t & 63;
  int col16 = lane & 15, quad = lane >> 4;
  f32x4 acc[3][4];
#pragma unroll
  for (int mi = 0; mi < 3; ++mi) {
#pragma unroll
    for (int r = 0; r < 4; ++r) {
      float bv = cb2[(wave * 3 + mi) * 16 + quad * 4 + r];
#pragma unroll
      for (int ni = 0; ni < 4; ++ni) acc[mi][ni][r] = bv;
    }
  }
  const ushort* wq = (const ushort*)wpk;
  for (int tap = 0; tap < 9; ++tap) {
    int dy = tap / 3, dx = tap % 3;
#pragma unroll
    for (int ks = 0; ks < 6; ++ks) {
      bf16x8 a[3];
#pragma unroll
      for (int mi = 0; mi < 3; ++mi) {
        int co = (wave * 3 + mi) * 16 + col16;
        a[mi] = *(const bf16x8*)(wq + ((size_t)tap * 192 + co) * 192 + ks * 32 + quad * 8);
      }
      bf16x8 bfr[4];
#pragma unroll
      for (int ni = 0; ni < 4; ++ni) {
        int p = (ni + dy) * 18 + col16 + dx;
        const bf16x4* src = (const bf16x4*)(&yl[p * 204 + ks * 32 + quad * 8]);
        union { bf16x8 v; bf16x4 h[2]; } u;
        u.h[0] = src[0];
        u.h[1] = src[1];
        bfr[ni] = u.v;
      }
#pragma unroll
      for (int mi = 0; mi < 3; ++mi)
#pragma unroll
        for (int ni = 0; ni < 4; ++ni)
          acc[mi][ni] = __builtin_amdgcn_mfma_f32_16x16x32_bf16(a[mi], bfr[ni], acc[mi][ni], 0, 0, 0);
    }
  }
#pragma unroll
  for (int mi = 0; mi < 3; ++mi) {
#pragma unroll
    for (int ni = 0; ni < 4; ++ni) {
#pragma unroll
      for (int r = 0; r < 4; ++r) {
        int co = (wave * 3 + mi) * 16 + quad * 4 + r;
        size_t off = (((size_t)b * C_ + co) * H_ + (h0 + ni)) * W_ + w0 + col16;
        float v = acc[mi][ni][r];
        v = (v >= 0.f) ? v : 0.1f * v;
        out[off] = out[off] + v;
      }
    }
  }
}

// ---------------------------------------------------------------------------
extern "C" void kernel_launch(void* const* d_in, const int* in_sizes, int n_in,
                              void* d_out, int out_size, void* d_ws, size_t ws_size,
                              hipStream_t stream) {
  const float* x      = (const float*)d_in[0];
  const float* ln_w   = (const float*)d_in[1];
  const float* qkv_w  = (const float*)d_in[2];
  const float* qkv_b  = (const float*)d_in[3];
  const float* proj_w = (const float*)d_in[4];
  const float* proj_b = (const float*)d_in[5];
  const float* b1_w   = (const float*)d_in[6];
  const float* b1_b   = (const float*)d_in[7];
  const float* b2_w   = (const float*)d_in[8];
  const float* b2_b   = (const float*)d_in[9];
  const float* cw1    = (const float*)d_in[10];
  const float* cb1    = (const float*)d_in[11];
  const float* cw2    = (const float*)d_in[12];
  const float* cb2    = (const float*)d_in[13];
  const int*   bidx   = (const int*)d_in[14];
  const float* bdelta = (const float*)d_in[15];
  float* out = (float*)d_out;

  char* ws = (char*)d_ws;
  float* bias   = (float*)ws;                        // 4096 f32 packed bias (16384 B)
  bf16*  wpk    = (bf16*)(ws + 16384);               // 9*192*192 bf16 (663552 B)
  float* rowsum = (float*)(ws + 16384 + 663552);     // 192 f32 (pad to 1024 B)
  bf16*  big    = (bf16*)(ws + 16384 + 663552 + 1024); // qkv (window layout) then y (ch-last)

  hipLaunchKernelGGL(k_prep, dim3(1296), dim3(256), 0, stream,
                     b1_w, b1_b, b2_w, b2_b, bidx, bdelta, cw2, ln_w, qkv_w,
                     bias, wpk, rowsum);
  hipLaunchKernelGGL(k_ln_qkv, dim3(4608), dim3(256), 0, stream,
                     x, ln_w, qkv_w, qkv_b, rowsum, big);
  hipLaunchKernelGGL(k_attn, dim3(4608), dim3(256), 0, stream,
                     big, bias, proj_w, proj_b, x, out);
  hipLaunchKernelGGL(k_conv1_glu, dim3(4608), dim3(256), 0, stream,
                     out, cw1, cb1, big);
  hipLaunchKernelGGL(k_conv2, dim3(4608), dim3(256), 0, stream,
                     big, wpk, cb2, out);
}

// Round 4
// 1444.926 us; speedup vs baseline: 3.7120x; 1.0625x over previous
//
#include <hip/hip_runtime.h>
#include <hip/hip_bf16.h>
#include <math.h>

#define B_ 8
#define C_ 192
#define H_ 192
#define W_ 192
#define NWH 24   // windows per spatial dim

typedef __hip_bfloat16 bf16;
typedef short bf16x8 __attribute__((ext_vector_type(8)));
typedef short bf16x4 __attribute__((ext_vector_type(4)));
typedef float f32x4 __attribute__((ext_vector_type(4)));
typedef float f32x16 __attribute__((ext_vector_type(16)));

__device__ __forceinline__ float bf2f(bf16 v) { return __bfloat162float(v); }
__device__ __forceinline__ bf16 f2bf(float v) { return __float2bfloat16(v); }

union bu { bf16 b; ushort u; };

__device__ __forceinline__ uint packbf2(float a, float b) {
  bu c0, c1; c0.b = f2bf(a); c1.b = f2bf(b);
  return (uint)c0.u | ((uint)c1.u << 16);
}

// ---------------------------------------------------------------------------
// K0: bias MLP + gather -> MFMA-register-layout packed bias (block 0),
//     qkv rowsums (block 1), cw2 repack to bf16 [tap][co][ci] (all blocks),
//     bf16 repacks of qkv_w / cw1 / proj_w (row-major, low block indices).
// ---------------------------------------------------------------------------
__global__ __launch_bounds__(256) void k_prep(
    const float* __restrict__ b1_w, const float* __restrict__ b1_b,
    const float* __restrict__ b2_w, const float* __restrict__ b2_b,
    const int* __restrict__ bias_index, const float* __restrict__ bias_delta,
    const float* __restrict__ cw2,
    const float* __restrict__ ln_w, const float* __restrict__ qkv_w,
    const float* __restrict__ cw1, const float* __restrict__ proj_w,
    float* __restrict__ bias_pk, bf16* __restrict__ wpk,
    float* __restrict__ rowsum,
    bf16* __restrict__ qkv_wb, bf16* __restrict__ cw1b,
    bf16* __restrict__ projwb) {
  int t = threadIdx.x;
  if (blockIdx.x == 0) {
    __shared__ float val[256];
    if (t < 225) {
      float dy = bias_delta[2 * t], dx = bias_delta[2 * t + 1];
      float acc = b2_b[0];
      for (int j = 0; j < 16; ++j) {
        float hj = b1_w[2 * j] * dy + b1_w[2 * j + 1] * dx + b1_b[j];
        float g = 0.5f * hj * (1.0f + erff(hj * 0.7071067811865475f));  // exact GELU
        acc += g * b2_w[j];
      }
      val[t] = acc;
    }
    __syncthreads();
    for (int i = t; i < 4096; i += 256) {
      int idx = bias_index[i];
      idx = min(max(idx, 0), 224);
      float v = val[idx];
      int q = i >> 6, k = i & 63;
      int nt = q >> 5, m = k >> 5, kl = k & 31;
      int hi2 = (kl >> 2) & 1, reg = (kl & 3) + 4 * (kl >> 3);
      bias_pk[((nt * 2 + m) * 16 + reg) * 64 + (q & 31) + 32 * hi2] = v;
    }
  }
  if (blockIdx.x == 1 && t < 192) {
    // rowsum[j] = sum_c qkv_w[j][c] * ln_w[c]   (for LN mean folding)
    float s = 0.f;
    for (int c = 0; c < C_; ++c) s += qkv_w[t * C_ + c] * ln_w[c];
    rowsum[t] = s;
  }
  // repack cw2 [co][ci][9] -> bf16 wpk[tap][co][ci]
  int idx = blockIdx.x * 256 + t;
  if (idx < 9 * 192 * 192) {
    int tp = idx / 36864;
    int r = idx % 36864;
    int co = r / 192, ci = r % 192;
    wpk[idx] = f2bf(cw2[(co * 192 + ci) * 9 + tp]);
  }
  // straight bf16 repacks (row-major preserved)
  if (idx < 36864) qkv_wb[idx] = f2bf(qkv_w[idx]);
  if (idx < 73728) cw1b[idx] = f2bf(cw1[idx]);
  if (idx < 12288) projwb[idx] = f2bf(proj_w[idx]);
}

// ---------------------------------------------------------------------------
// K1: per-pixel LayerNorm over C + QKV GEMM as MFMA implicit GEMM.
// Linearity trick: W·((x-mu)/sig*g) = (1/sig)·(W·(g*x) - mu·rowsum).
// Output layout: WINDOW-CONTIGUOUS qkv[win][192ch][64px] bf16.
// ---------------------------------------------------------------------------
__global__ __launch_bounds__(256) void k_ln_qkv(
    const float* __restrict__ x, const float* __restrict__ ln_w,
    const bf16* __restrict__ qkv_wb, const float* __restrict__ qkv_b,
    const float* __restrict__ rowsum, bf16* __restrict__ qkv) {
  __shared__ ushort xs[64 * 204];   // bf16 (g*x), [pixel][ci], stride 204
  __shared__ float red[512];
  __shared__ float mus[64], rsigs[64];
  int t = threadIdx.x;
  int blk = blockIdx.x;
  int b = blk / (H_ * 3);
  int rem = blk % (H_ * 3);
  int h = rem / 3;
  int w0 = (rem % 3) * 64;
  int p = t & 63, q = t >> 6;
  const float* xb = x + ((size_t)b * C_ * H_ + h) * W_ + w0;
  float s = 0.f, s2 = 0.f;
  for (int c = q; c < C_; c += 4) {
    float v = xb[(size_t)c * H_ * W_ + p];
    s += v; s2 += v * v;
    bu cv; cv.b = f2bf(v * ln_w[c]);
    xs[p * 204 + c] = cv.u;
  }
  red[q * 64 + p] = s;
  red[256 + q * 64 + p] = s2;
  __syncthreads();
  if (t < 64) {
    float su = red[t] + red[64 + t] + red[128 + t] + red[192 + t];
    float su2 = red[256 + t] + red[320 + t] + red[384 + t] + red[448 + t];
    float mu = su * (1.f / 192.f);
    float m2 = su2 * (1.f / 192.f);
    mus[t] = mu;
    rsigs[t] = rsqrtf(m2 - mu * mu + 1e-5f);
  }
  __syncthreads();

  int wave = t >> 6, lane = t & 63;
  int col16 = lane & 15, quad = lane >> 4;
  f32x4 acc[3][4];
#pragma unroll
  for (int mi = 0; mi < 3; ++mi)
#pragma unroll
    for (int ni = 0; ni < 4; ++ni)
#pragma unroll
      for (int r = 0; r < 4; ++r) acc[mi][ni][r] = 0.f;

  const ushort* wqv = (const ushort*)qkv_wb;
  for (int ksi = 0; ksi < 6; ++ksi) {
    bf16x8 bfr[4];
#pragma unroll
    for (int ni = 0; ni < 4; ++ni) {
      const bf16x4* src =
          (const bf16x4*)(&xs[(ni * 16 + col16) * 204 + ksi * 32 + quad * 8]);
      union { bf16x8 v; bf16x4 h[2]; } u;
      u.h[0] = src[0];
      u.h[1] = src[1];
      bfr[ni] = u.v;
    }
#pragma unroll
    for (int mi = 0; mi < 3; ++mi) {
      int co = wave * 48 + mi * 16 + col16;
      bf16x8 a = *(const bf16x8*)(wqv + (size_t)co * 192 + ksi * 32 + quad * 8);
#pragma unroll
      for (int ni = 0; ni < 4; ++ni)
        acc[mi][ni] =
            __builtin_amdgcn_mfma_f32_16x16x32_bf16(a, bfr[ni], acc[mi][ni], 0, 0, 0);
    }
  }

  // epilogue: qkv = rsig*(acc - mu*rowsum) + b  -> window layout
  size_t winbase = ((size_t)b * 24 + (h >> 3)) * 24 + (w0 >> 3);
  int hw8 = (h & 7) * 8;
  ushort* ob = (ushort*)qkv;
#pragma unroll
  for (int mi = 0; mi < 3; ++mi) {
    int cob = wave * 48 + mi * 16 + quad * 4;
#pragma unroll
    for (int r = 0; r < 4; ++r) {
      int co = cob + r;
      float rs = rowsum[co];
      float bv = qkv_b[co];
#pragma unroll
      for (int ni = 0; ni < 4; ++ni) {
        int px = ni * 16 + col16;
        float v = rsigs[px] * (acc[mi][ni][r] - mus[px] * rs) + bv;
        size_t off = ((winbase + (px >> 3)) * 192 + co) * 64 + hw8 + (px & 7);
        bu cv; cv.b = f2bf(v);
        ob[off] = cv.u;
      }
    }
  }
}

// ---------------------------------------------------------------------------
// K2: windowed attention, full MFMA.  Block = one 8x8 window, wave = head.
// ---------------------------------------------------------------------------
__global__ __launch_bounds__(256) void k_attn(
    const bf16* __restrict__ qkv, const float* __restrict__ bias_pk,
    const bf16* __restrict__ projwb, const float* __restrict__ proj_b,
    const float* __restrict__ x, float* __restrict__ out) {
  __shared__ ushort qkvL[192 * 68];   // [ch][px], 26112 B; rows 0..63 reused as os[px][ch]
  int t = threadIdx.x;
  int blk = blockIdx.x;
  int b = blk / (NWH * NWH);
  int rem = blk % (NWH * NWH);
  int wh = rem / NWH, ww = rem % NWH;
  int h0 = wh * 8, w0 = ww * 8;
  int lane = t & 63, hd = t >> 6;
  int l31 = lane & 31, hi = lane >> 5;
  int col16 = lane & 15, quad = lane >> 4;

  // ---- stage qkv window (fully coalesced 16B loads) ----
  const ushort* qg = (const ushort*)qkv + (size_t)blk * 12288;
#pragma unroll
  for (int i = 0; i < 6; ++i) {
    int e = i * 256 + t;
    int ch = e >> 3, chunk = e & 7;
    uint4 v = *(const uint4*)(qg + ch * 64 + chunk * 8);
    ushort* dst = &qkvL[ch * 68 + chunk * 8];
    *(uint2*)dst = make_uint2(v.x, v.y);
    *(uint2*)(dst + 4) = make_uint2(v.z, v.w);
  }
  __syncthreads();

  // ---- QK^T (swapped): S^T[key][q], 2x2 tiles of 32x32, K=16 ----
  bf16x8 ka[2], qb[2];
#pragma unroll
  for (int m = 0; m < 2; ++m) {
    union { bf16x8 v; ushort s[8]; } u;
#pragma unroll
    for (int j = 0; j < 8; ++j)
      u.s[j] = qkvL[(64 + hd * 16 + hi * 8 + j) * 68 + m * 32 + l31];
    ka[m] = u.v;
  }
#pragma unroll
  for (int n = 0; n < 2; ++n) {
    union { bf16x8 v; ushort s[8]; } u;
#pragma unroll
    for (int j = 0; j < 8; ++j)
      u.s[j] = qkvL[(hd * 16 + hi * 8 + j) * 68 + n * 32 + l31];
    qb[n] = u.v;
  }
  f32x16 accs[2][2];
#pragma unroll
  for (int m = 0; m < 2; ++m)
#pragma unroll
    for (int n = 0; n < 2; ++n) {
#pragma unroll
      for (int r = 0; r < 16; ++r) accs[m][n][r] = 0.f;
      accs[m][n] = __builtin_amdgcn_mfma_f32_32x32x16_bf16(ka[m], qb[n], accs[m][n], 0, 0, 0);
    }
  __syncthreads();   // all Q/K reads done (os will alias that region)

  // ---- softmax (lane-local + one shfl_xor(32)); P packed to bf16 pairs ----
  uint pk[2][2][8];
#pragma unroll
  for (int nt = 0; nt < 2; ++nt) {
    float sc[2][16];
#pragma unroll
    for (int m = 0; m < 2; ++m)
#pragma unroll
      for (int r = 0; r < 16; ++r)
        sc[m][r] = fmaf(accs[m][nt][r], 0.25f,
                        bias_pk[((nt * 2 + m) * 16 + r) * 64 + lane]);
    float m8[8];
#pragma unroll
    for (int r = 0; r < 8; ++r)
      m8[r] = fmaxf(fmaxf(sc[0][r], sc[0][r + 8]), fmaxf(sc[1][r], sc[1][r + 8]));
    float mx = fmaxf(fmaxf(fmaxf(m8[0], m8[1]), fmaxf(m8[2], m8[3])),
                     fmaxf(fmaxf(m8[4], m8[5]), fmaxf(m8[6], m8[7])));
    mx = fmaxf(mx, __shfl_xor(mx, 32));
    float s8[8];
#pragma unroll
    for (int r = 0; r < 8; ++r) {
      float e0 = __expf(sc[0][r] - mx);      sc[0][r] = e0;
      float e1 = __expf(sc[0][r + 8] - mx);  sc[0][r + 8] = e1;
      float e2 = __expf(sc[1][r] - mx);      sc[1][r] = e2;
      float e3 = __expf(sc[1][r + 8] - mx);  sc[1][r + 8] = e3;
      s8[r] = (e0 + e1) + (e2 + e3);
    }
    float sum = ((s8[0] + s8[1]) + (s8[2] + s8[3])) + ((s8[4] + s8[5]) + (s8[6] + s8[7]));
    sum += __shfl_xor(sum, 32);
    float inv = 1.f / sum;
#pragma unroll
    for (int m = 0; m < 2; ++m)
#pragma unroll
      for (int rp = 0; rp < 8; ++rp)
        pk[nt][m][rp] = packbf2(sc[m][2 * rp] * inv, sc[m][2 * rp + 1] * inv);
  }

  // ---- PV: O[q][d] = P·V, 2 m-tiles of 32x32, K=16 per step (4 steps) ----
  f32x16 acco[2];
#pragma unroll
  for (int mt = 0; mt < 2; ++mt) {
#pragma unroll
    for (int r = 0; r < 16; ++r) acco[mt][r] = 0.f;
    uint sw[2][8];
#pragma unroll
    for (int mb = 0; mb < 2; ++mb)
#pragma unroll
      for (int rp = 0; rp < 8; ++rp)
        sw[mb][rp] = __shfl_xor(pk[mt][mb][rp], 32);
#pragma unroll
    for (int kc = 0; kc < 4; ++kc) {
      int mb = kc >> 1, r0 = (kc & 1) * 4;
      union { bf16x8 v; uint d[4]; } af;
      af.d[0] = hi ? sw[mb][r0 + 2] : pk[mt][mb][r0 + 0];
      af.d[1] = hi ? sw[mb][r0 + 3] : pk[mt][mb][r0 + 1];
      af.d[2] = hi ? pk[mt][mb][r0 + 2] : sw[mb][r0 + 0];
      af.d[3] = hi ? pk[mt][mb][r0 + 3] : sw[mb][r0 + 1];
      union { bf16x8 v; uint2 h[2]; } bv;
      const ushort* vsrc = &qkvL[(128 + hd * 16 + col16) * 68 + kc * 16 + hi * 8];
      bv.h[0] = *(const uint2*)(vsrc);
      bv.h[1] = *(const uint2*)(vsrc + 4);
      acco[mt] = __builtin_amdgcn_mfma_f32_32x32x16_bf16(af.v, bv.v, acco[mt], 0, 0, 0);
    }
  }
  // ---- O -> os LDS (aliased over Q/K rows), layout os[px][68] ch-contig ----
  if (l31 < 16) {
#pragma unroll
    for (int mt = 0; mt < 2; ++mt)
#pragma unroll
      for (int r = 0; r < 16; ++r) {
        int qrow = mt * 32 + (r & 3) + 8 * (r >> 2) + 4 * hi;
        bu cv; cv.b = f2bf(acco[mt][r]);
        qkvL[qrow * 68 + hd * 16 + l31] = cv.u;
      }
  }
  __syncthreads();

  // ---- proj: M=192 co, N=64 px, K=64; wave hd owns co [48hd, 48hd+48) ----
  f32x4 accp[3][4];
#pragma unroll
  for (int mi = 0; mi < 3; ++mi)
#pragma unroll
    for (int r = 0; r < 4; ++r) {
      float bv = proj_b[hd * 48 + mi * 16 + quad * 4 + r];
#pragma unroll
      for (int ni = 0; ni < 4; ++ni) accp[mi][ni][r] = bv;
    }
  const ushort* wpj = (const ushort*)projwb;
#pragma unroll
  for (int kc = 0; kc < 2; ++kc) {
    bf16x8 bos[4];
#pragma unroll
    for (int ni = 0; ni < 4; ++ni) {
      const ushort* src = &qkvL[(ni * 16 + col16) * 68 + kc * 32 + quad * 8];
      union { bf16x8 v; uint2 h[2]; } u;
      u.h[0] = *(const uint2*)(src);
      u.h[1] = *(const uint2*)(src + 4);
      bos[ni] = u.v;
    }
#pragma unroll
    for (int mi = 0; mi < 3; ++mi) {
      bf16x8 a = *(const bf16x8*)(wpj + (size_t)(hd * 48 + mi * 16 + col16) * 64 +
                                  kc * 32 + quad * 8);
#pragma unroll
      for (int ni = 0; ni < 4; ++ni)
        accp[mi][ni] = __builtin_amdgcn_mfma_f32_16x16x32_bf16(a, bos[ni], accp[mi][ni], 0, 0, 0);
    }
  }
  // ---- residual add + store ----
  size_t base = ((size_t)b * C_ * H_ + h0) * W_ + w0;
#pragma unroll
  for (int mi = 0; mi < 3; ++mi) {
#pragma unroll
    for (int ni = 0; ni < 4; ++ni) {
#pragma unroll
      for (int r = 0; r < 4; ++r) {
        int co = hd * 48 + mi * 16 + quad * 4 + r;
        int px = ni * 16 + col16;
        size_t off = base + (size_t)co * H_ * W_ + (size_t)(px >> 3) * W_ + (px & 7);
        out[off] = accp[mi][ni][r] + x[off];
      }
    }
  }
}

// ---------------------------------------------------------------------------
// K3: 1x1 conv (C->2C) + GLU as implicit GEMM on MFMA.
// ---------------------------------------------------------------------------
__global__ __launch_bounds__(256) void k_conv1_glu(
    const float* __restrict__ xa, const bf16* __restrict__ cw1b,
    const float* __restrict__ cb1, bf16* __restrict__ y) {
  __shared__ ushort xs[64 * 204];   // bf16 [pixel][ci], stride 204 (2-way alias max)
  int t = threadIdx.x;
  int blk = blockIdx.x;
  int b = blk / (H_ * 3);
  int rem = blk % (H_ * 3);
  int h = rem / 3;
  int w0 = (rem % 3) * 64;
  int p = t & 63, q = t >> 6;
  const float* xb = xa + ((size_t)b * C_ * H_ + h) * W_ + w0;
  for (int c = q; c < C_; c += 4) {
    bu cv; cv.b = f2bf(xb[(size_t)c * H_ * W_ + p]);
    xs[p * 204 + c] = cv.u;
  }
  __syncthreads();

  int wave = t >> 6, lane = t & 63;
  int col16 = lane & 15, quad = lane >> 4;
  f32x4 acc[6][4];
#pragma unroll
  for (int mi = 0; mi < 6; ++mi) {
    int cob = (mi < 3) ? wave * 48 + mi * 16 : 192 + wave * 48 + (mi - 3) * 16;
#pragma unroll
    for (int r = 0; r < 4; ++r) {
      float bv = cb1[cob + quad * 4 + r];
#pragma unroll
      for (int ni = 0; ni < 4; ++ni) acc[mi][ni][r] = bv;
    }
  }

  const ushort* wc1 = (const ushort*)cw1b;
  for (int ksi = 0; ksi < 6; ++ksi) {
    bf16x8 bfr[4];
#pragma unroll
    for (int ni = 0; ni < 4; ++ni) {
      const bf16x4* src =
          (const bf16x4*)(&xs[(ni * 16 + col16) * 204 + ksi * 32 + quad * 8]);
      union { bf16x8 v; bf16x4 h[2]; } u;
      u.h[0] = src[0];
      u.h[1] = src[1];
      bfr[ni] = u.v;
    }
#pragma unroll
    for (int mi = 0; mi < 6; ++mi) {
      int cob = (mi < 3) ? wave * 48 + mi * 16 : 192 + wave * 48 + (mi - 3) * 16;
      bf16x8 a = *(const bf16x8*)(wc1 + (size_t)(cob + col16) * 192 + ksi * 32 + quad * 8);
#pragma unroll
      for (int ni = 0; ni < 4; ++ni)
        acc[mi][ni] =
            __builtin_amdgcn_mfma_f32_16x16x32_bf16(a, bfr[ni], acc[mi][ni], 0, 0, 0);
    }
  }
  __syncthreads();   // all xs reads done; reuse xs for output staging

#pragma unroll
  for (int mi = 0; mi < 3; ++mi) {
#pragma unroll
    for (int ni = 0; ni < 4; ++ni) {
      int px = ni * 16 + col16;
      int co = wave * 48 + mi * 16 + quad * 4;
#pragma unroll
      for (int rr = 0; rr < 2; ++rr) {
        float a0 = acc[mi][ni][rr * 2], a1 = acc[mi][ni][rr * 2 + 1];
        float g0 = acc[mi + 3][ni][rr * 2], g1 = acc[mi + 3][ni][rr * 2 + 1];
        float r0 = a0 / (1.f + __expf(-g0));
        float r1 = a1 / (1.f + __expf(-g1));
        bu c0, c1;
        c0.b = f2bf(r0); c1.b = f2bf(r1);
        *(uint*)(&xs[px * 204 + co + rr * 2]) = (uint)c0.u | ((uint)c1.u << 16);
      }
    }
  }
  __syncthreads();
  ushort* yb = (ushort*)y + (((size_t)b * H_ + h) * W_ + w0) * 192;
#pragma unroll
  for (int i = 0; i < 6; ++i) {
    int e = i * 256 + t;
    int px = e / 24, ch = e % 24;
    uint u0 = *(const uint*)(&xs[px * 204 + ch * 8]);
    uint u1 = *(const uint*)(&xs[px * 204 + ch * 8 + 2]);
    uint u2 = *(const uint*)(&xs[px * 204 + ch * 8 + 4]);
    uint u3 = *(const uint*)(&xs[px * 204 + ch * 8 + 6]);
    uint4 pkv; pkv.x = u0; pkv.y = u1; pkv.z = u2; pkv.w = u3;
    *(uint4*)(yb + (size_t)px * 192 + ch * 8) = pkv;
  }
}

// ---------------------------------------------------------------------------
// K4: 3x3 conv as implicit GEMM on MFMA, 2-deep ping-pong software pipeline
// over the flattened 54-step (tap,ks) loop: prefetch A (global/L2) and B
// (LDS) fragments for step it+1 before issuing the 12 MFMAs of step it.
// ---------------------------------------------------------------------------
__global__ __launch_bounds__(256) void k_conv2(
    const bf16* __restrict__ y, const bf16* __restrict__ wpk,
    const float* __restrict__ cb2, float* __restrict__ out) {
  __shared__ ushort yl[6 * 18 * 204];  // [halo pixel][ci], 44064 B
  int t = threadIdx.x;
  int blk = blockIdx.x;
  int b = blk / (48 * 12);
  int rem = blk % (48 * 12);
  int h0 = (rem / 12) * 4;
  int w0 = (rem % 12) * 16;
  const ushort* yg = (const ushort*)y;
  for (int e = t; e < 108 * 48; e += 256) {
    int p = e / 48, c8 = e % 48;
    int prow = p / 18, pcol = p % 18;
    int gr = min(max(h0 - 1 + prow, 0), H_ - 1);
    int gc = min(max(w0 - 1 + pcol, 0), W_ - 1);
    *(float2*)(&yl[p * 204 + c8 * 4]) =
        *(const float2*)(yg + (((size_t)b * H_ + gr) * W_ + gc) * 192 + c8 * 4);
  }
  __syncthreads();
  int wave = t >> 6, lane = t & 63;
  int col16 = lane & 15, quad = lane >> 4;
  f32x4 acc[3][4];
#pragma unroll
  for (int mi = 0; mi < 3; ++mi) {
#pragma unroll
    for (int r = 0; r < 4; ++r) {
      float bv = cb2[(wave * 3 + mi) * 16 + quad * 4 + r];
#pragma unroll
      for (int ni = 0; ni < 4; ++ni) acc[mi][ni][r] = bv;
    }
  }
  const ushort* wq = (const ushort*)wpk;
  int co0 = wave * 48 + col16;

  auto loada = [&](int tap, int ks, bf16x8 (&dst)[3]) {
#pragma unroll
    for (int mi = 0; mi < 3; ++mi)
      dst[mi] = *(const bf16x8*)(wq + ((size_t)tap * 192 + co0 + mi * 16) * 192 +
                                 ks * 32 + quad * 8);
  };
  auto loadb = [&](int tap, int ks, bf16x8 (&dst)[4]) {
    int dy = tap / 3, dx = tap % 3;
#pragma unroll
    for (int ni = 0; ni < 4; ++ni) {
      int p = (ni + dy) * 18 + col16 + dx;
      const bf16x4* src = (const bf16x4*)(&yl[p * 204 + ks * 32 + quad * 8]);
      union { bf16x8 v; bf16x4 h[2]; } u;
      u.h[0] = src[0];
      u.h[1] = src[1];
      dst[ni] = u.v;
    }
  };

  bf16x8 aA[3], bA[4], aB[3], bB[4];
  loada(0, 0, aA);
  loadb(0, 0, bA);
  int ntap = 0, nks = 1;
  for (int it = 0; it < 54; it += 2) {
    // prefetch step it+1 into B buffers
    loada(ntap, nks, aB);
    loadb(ntap, nks, bB);
    ++nks; if (nks == 6) { nks = 0; ++ntap; }
#pragma unroll
    for (int mi = 0; mi < 3; ++mi)
#pragma unroll
      for (int ni = 0; ni < 4; ++ni)
        acc[mi][ni] = __builtin_amdgcn_mfma_f32_16x16x32_bf16(aA[mi], bA[ni], acc[mi][ni], 0, 0, 0);
    // prefetch step it+2 into A buffers
    if (it + 2 < 54) {
      loada(ntap, nks, aA);
      loadb(ntap, nks, bA);
      ++nks; if (nks == 6) { nks = 0; ++ntap; }
    }
#pragma unroll
    for (int mi = 0; mi < 3; ++mi)
#pragma unroll
      for (int ni = 0; ni < 4; ++ni)
        acc[mi][ni] = __builtin_amdgcn_mfma_f32_16x16x32_bf16(aB[mi], bB[ni], acc[mi][ni], 0, 0, 0);
  }
#pragma unroll
  for (int mi = 0; mi < 3; ++mi) {
#pragma unroll
    for (int ni = 0; ni < 4; ++ni) {
#pragma unroll
      for (int r = 0; r < 4; ++r) {
        int co = (wave * 3 + mi) * 16 + quad * 4 + r;
        size_t off = (((size_t)b * C_ + co) * H_ + (h0 + ni)) * W_ + w0 + col16;
        float v = acc[mi][ni][r];
        v = (v >= 0.f) ? v : 0.1f * v;
        out[off] = out[off] + v;
      }
    }
  }
}

// ---------------------------------------------------------------------------
extern "C" void kernel_launch(void* const* d_in, const int* in_sizes, int n_in,
                              void* d_out, int out_size, void* d_ws, size_t ws_size,
                              hipStream_t stream) {
  const float* x      = (const float*)d_in[0];
  const float* ln_w   = (const float*)d_in[1];
  const float* qkv_w  = (const float*)d_in[2];
  const float* qkv_b  = (const float*)d_in[3];
  const float* proj_w = (const float*)d_in[4];
  const float* proj_b = (const float*)d_in[5];
  const float* b1_w   = (const float*)d_in[6];
  const float* b1_b   = (const float*)d_in[7];
  const float* b2_w   = (const float*)d_in[8];
  const float* b2_b   = (const float*)d_in[9];
  const float* cw1    = (const float*)d_in[10];
  const float* cb1    = (const float*)d_in[11];
  const float* cw2    = (const float*)d_in[12];
  const float* cb2    = (const float*)d_in[13];
  const int*   bidx   = (const int*)d_in[14];
  const float* bdelta = (const float*)d_in[15];
  float* out = (float*)d_out;

  char* ws = (char*)d_ws;
  float* bias   = (float*)ws;                          // 4096 f32 packed bias (16384 B)
  bf16*  wpk    = (bf16*)(ws + 16384);                 // 9*192*192 bf16 (663552 B)
  float* rowsum = (float*)(ws + 679936);               // 192 f32 (1024 B)
  bf16*  qkv_wb = (bf16*)(ws + 680960);                // 36864 bf16 (73728 B)
  bf16*  cw1b   = (bf16*)(ws + 754688);                // 73728 bf16 (147456 B)
  bf16*  projwb = (bf16*)(ws + 902144);                // 12288 bf16 (24576 B)
  bf16*  big    = (bf16*)(ws + 926720);                // qkv (window layout) then y (ch-last)

  hipLaunchKernelGGL(k_prep, dim3(1296), dim3(256), 0, stream,
                     b1_w, b1_b, b2_w, b2_b, bidx, bdelta, cw2, ln_w, qkv_w,
                     cw1, proj_w, bias, wpk, rowsum, qkv_wb, cw1b, projwb);
  hipLaunchKernelGGL(k_ln_qkv, dim3(4608), dim3(256), 0, stream,
                     x, ln_w, qkv_wb, qkv_b, rowsum, big);
  hipLaunchKernelGGL(k_attn, dim3(4608), dim3(256), 0, stream,
                     big, bias, projwb, proj_b, x, out);
  hipLaunchKernelGGL(k_conv1_glu, dim3(4608), dim3(256), 0, stream,
                     out, cw1b, cb1, big);
  hipLaunchKernelGGL(k_conv2, dim3(4608), dim3(256), 0, stream,
                     big, wpk, cb2, out);
}